// Round 1
// 240.022 us; speedup vs baseline: 1.0670x; 1.0670x over previous
//
#include <hip/hip_runtime.h>

// ---------------------------------------------------------------------------
// CustomMultiHeadAttentionStoich: fused MHA with RoPE + frac-difference bias.
// B=2 T=2048 D_MODEL=1024 H=16 hd=64. All matmuls via mfma_f32_16x16x32_bf16.
//
// Verified gfx950 fragment layouts (learn_hip m89/m91, rounds 1-6 pass):
//   A-frag : lane holds A[m=lane&15][k=(lane>>4)*8 + j], j=0..7  (8 bf16, 16B)
//   B-frag : lane holds B[k=(lane>>4)*8 + j][n=lane&15]
//   C/D    : lane holds D[row=(lane>>4)*4 + r][col=lane&15], r=0..3 (4 f32)
//
// Round-8 changes (k_attn only; occupancy was the limiter: grid 512 blocks x
// 4 waves = 2 waves/SIMD, VALUBusy 45%, all pipes <50%):
//  * k_attn: 512 threads / 8 waves. Waves 0-3 process keys [0,32) of each
//    64-key tile, waves 4-7 keys [32,64), same four 32-row q sub-tiles.
//    Softmax is exp2-native WITHOUT max subtraction, so key-partitions merge
//    exactly: per-half unnormalized (O,l) summed once at the end via LDS.
//    Aggregate MFMA/VALU/LDS/DMA traffic unchanged; waves/SIMD 2 -> 4.
//    __launch_bounds__(512,4) caps VGPR at 128 (prev build: 92).
//  * P tile stride 72 -> 40 elems (80 B: keeps ds b128 16-B alignment;
//    b64 write 4-way, b128 read 8-way = conflict-free minimum). LDS 53 KB.
//  * bias: (dd>=0?ap:an)*dd  ->  c1*dd + c2*|dd|  (saves cmp+cndmask/score).
// ---------------------------------------------------------------------------

typedef unsigned short u16;
typedef __bf16 bf8v __attribute__((ext_vector_type(8)));
typedef __bf16 bf4v __attribute__((ext_vector_type(4)));
typedef float f32x4 __attribute__((ext_vector_type(4)));

#define D_MODEL 1024
#define T_SEQ   2048
#define NHEAD   16
#define HDIM    64
#define BATCH   2
#define M_TOT   (BATCH * T_SEQ) /* 4096 */
#define LOG2E   1.4426950408889634f

__device__ __forceinline__ void gl2lds16(const u16* g, u16* l) {
  __builtin_amdgcn_global_load_lds(
      (__attribute__((address_space(1))) void*)g,
      (__attribute__((address_space(3))) void*)l, 16, 0, 0);
}

// ---------------------------------------------------------------------------
// k_prep: zone-partitioned prep work in ONE launch.
//   blocks [0,6144)    : f32->bf16 convert of q/k/v into Xb
//   blocks [6144,7168) : W^T bf16 transpose of Wq/Wk/Wv/Wo into WtB
//   blocks [7168,7424) : RoPE cos/sin table
__global__ __launch_bounds__(256) void k_prep(
    const float* __restrict__ q, const float* __restrict__ k,
    const float* __restrict__ v, const float* __restrict__ Wq,
    const float* __restrict__ Wk, const float* __restrict__ Wv,
    const float* __restrict__ Wo, u16* __restrict__ Xb, u16* __restrict__ WtB,
    float* __restrict__ ct, float* __restrict__ st) {
  __shared__ float tile[64 * 65];
  int bx = blockIdx.x, tid = threadIdx.x;
  if (bx < 6144) { // ---- convert zone
    int z = bx >> 11, xb = bx & 2047;
    const float* src = (z == 0) ? q : (z == 1) ? k : v;
    u16* dst = Xb + (size_t)z * (M_TOT * D_MODEL);
    int idx = (xb * 256 + tid) * 8;
    float4 a = *(const float4*)(src + idx);
    float4 b = *(const float4*)(src + idx + 4);
    bf8v o;
    o[0] = (__bf16)a.x; o[1] = (__bf16)a.y; o[2] = (__bf16)a.z; o[3] = (__bf16)a.w;
    o[4] = (__bf16)b.x; o[5] = (__bf16)b.y; o[6] = (__bf16)b.z; o[7] = (__bf16)b.w;
    *(bf8v*)(dst + idx) = o;
  } else if (bx < 7168) { // ---- W transpose zone (64x64 tiles, stride 65)
    int idx2 = bx - 6144;
    int z = idx2 >> 8, rem = idx2 & 255;
    int k0 = (rem >> 4) * 64, n0 = (rem & 15) * 64;
    const float* W = (z == 0) ? Wq : (z == 1) ? Wk : (z == 2) ? Wv : Wo;
    u16* Wt = WtB + (size_t)z * (D_MODEL * D_MODEL);
#pragma unroll
    for (int i = 0; i < 16; i++) {
      int idx = tid + i * 256;
      int r = idx >> 6, c = idx & 63;
      tile[c * 65 + r] = W[(size_t)(k0 + r) * D_MODEL + n0 + c];
    }
    __syncthreads();
#pragma unroll
    for (int i = 0; i < 16; i++) {
      int idx = tid + i * 256;
      int r = idx >> 6, c = idx & 63;
      ((__bf16*)Wt)[(size_t)(n0 + r) * D_MODEL + k0 + c] = (__bf16)tile[r * 65 + c];
    }
  } else { // ---- RoPE table zone: angle(t,d) = t / 10000^(d/32)
    int idx = (bx - 7168) * 256 + tid; // = t*32 + d
    int t = idx >> 5, d = idx & 31;
    float ang = (float)t * powf(10000.0f, -(float)d * (1.0f / 32.0f));
    ct[idx] = cosf(ang);
    st[idx] = sinf(ang);
  }
}

// ---------------------------------------------------------------------------
// QKV GEMM core (r4/r6 structure): C = A[M][K] @ Bt[N][K]^T, K=1024, BK=64
// (two stride-32 planes per operand, bank-balanced b128 frag reads).
// 2-barrier single-buffer global_load_lds staging. BM=128, BN=128.
__device__ __forceinline__ void gemm_core_128(const u16* __restrict__ A,
                                              const u16* __restrict__ Bt,
                                              u16* sA, u16* sB,
                                              f32x4 (&acc)[4][4],
                                              int m0, int n0) {
  const int K = D_MODEL;
  int tid = threadIdx.x;
  int lane = tid & 63, wave = tid >> 6;
  int l15 = lane & 15, quad = lane >> 4;
  int wm = (wave >> 1) * 64, wn = (wave & 1) * 64;
  int r0 = tid >> 2, pcol0 = (tid & 3) * 8;
  int r1 = 64 + r0;
  const u16* A0 = A + (size_t)(m0 + r0) * K + pcol0;
  const u16* A1 = A + (size_t)(m0 + r1) * K + pcol0;
  const u16* B0 = Bt + (size_t)(n0 + r0) * K + pcol0;
  const u16* B1 = Bt + (size_t)(n0 + r1) * K + pcol0;
  u16* dA0 = sA + wave * 512;        // plane0, rows 0..63 (wave-uniform base)
  u16* dA1 = sA + 2048 + wave * 512; // plane0, rows 64..127
  u16* dB0 = sB + wave * 512;
  u16* dB1 = sB + 2048 + wave * 512;
  for (int k0 = 0; k0 < K; k0 += 64) {
    __syncthreads(); // previous iter's frag reads done
    gl2lds16(A0 + k0, dA0);
    gl2lds16(A1 + k0, dA1);
    gl2lds16(A0 + k0 + 32, dA0 + 4096); // plane1
    gl2lds16(A1 + k0 + 32, dA1 + 4096);
    gl2lds16(B0 + k0, dB0);
    gl2lds16(B0 + k0 + 32, dB0 + 4096);
    gl2lds16(B1 + k0, dB1);
    gl2lds16(B1 + k0 + 32, dB1 + 4096);
    __syncthreads(); // barrier drain -> LDS data visible
#pragma unroll
    for (int kh = 0; kh < 2; kh++) {
      bf8v af[4], bf[4];
#pragma unroll
      for (int i = 0; i < 4; i++)
        af[i] = *(const bf8v*)(sA + kh * 4096 + (wm + i * 16 + l15) * 32 + quad * 8);
#pragma unroll
      for (int i = 0; i < 4; i++)
        bf[i] = *(const bf8v*)(sB + kh * 4096 + (wn + i * 16 + l15) * 32 + quad * 8);
#pragma unroll
      for (int mi = 0; mi < 4; mi++)
#pragma unroll
        for (int ni = 0; ni < 4; ni++)
          acc[mi][ni] = __builtin_amdgcn_mfma_f32_16x16x32_bf16(
              af[mi], bf[ni], acc[mi][ni], 0, 0, 0);
    }
  }
}

// QKV projection, grid (8, 32, 3). z<2 -> RoPE fused; z==0 prescales Q by
// 0.125*log2e. z==2 writes projected V DIRECTLY TRANSPOSED into Vb[b][h][d][t].
__global__ __launch_bounds__(256) void k_gemm_qkv(
    const u16* __restrict__ Xb, const u16* __restrict__ WtB,
    const float* __restrict__ bq, const float* __restrict__ bk,
    const float* __restrict__ bv, const float* __restrict__ ctab,
    const float* __restrict__ stab, u16* __restrict__ OutB,
    u16* __restrict__ Vb) {
  __shared__ __align__(16) u16 sA[128 * 64];
  __shared__ __align__(16) u16 sB[128 * 64];
  int z = blockIdx.z;
  const u16* A = Xb + (size_t)z * (M_TOT * D_MODEL);
  const u16* Bt = WtB + (size_t)z * (D_MODEL * D_MODEL);
  const float* bias = (z == 0) ? bq : (z == 1) ? bk : bv;
  u16* Out = OutB + (size_t)z * (M_TOT * D_MODEL);
  int m0 = blockIdx.y * 128, n0 = blockIdx.x * 128;
  f32x4 acc[4][4] = {};
  gemm_core_128(A, Bt, sA, sB, acc, m0, n0);

  int tid = threadIdx.x, lane = tid & 63, wave = tid >> 6;
  int l15 = lane & 15, quad = lane >> 4;
  int wm = (wave >> 1) * 64, wn = (wave & 1) * 64;
  float bvv[4];
#pragma unroll
  for (int ni = 0; ni < 4; ni++) bvv[ni] = bias[n0 + wn + ni * 16 + l15];

  if (z < 2) { // Q/K: RoPE fused; Q also prescaled 0.125*log2e
    float qs = (z == 0) ? 0.125f * LOG2E : 1.0f;
#pragma unroll
    for (int mi = 0; mi < 4; mi++) {
#pragma unroll
      for (int r = 0; r < 4; r++) {
        int m = m0 + wm + mi * 16 + quad * 4 + r; // global row = b*T + t
        size_t ro = (size_t)m * D_MODEL + n0 + wn;
        int tl = m & (T_SEQ - 1);
#pragma unroll
        for (int ni = 0; ni < 2; ni++) {
          int d = ni * 16 + l15; // < 32; pair (d, d+32) in regs ni, ni+2
          float c = ctab[tl * 32 + d], s = stab[tl * 32 + d];
          float xl = acc[mi][ni][r] + bvv[ni];
          float xr = acc[mi][ni + 2][r] + bvv[ni + 2];
          ((__bf16*)Out)[ro + d] = (__bf16)((xl * c - xr * s) * qs);
          ((__bf16*)Out)[ro + d + 32] = (__bf16)((xl * s + xr * c) * qs);
        }
      }
    }
  } else { // V: write transposed Vb[b][h][d][t] (wave's 64 cols = one head)
    int hh = (n0 + wn) >> 6;
    int mbase = m0 + wm;
    int bb = mbase >> 11; // tile never crosses batch (2048 % 128 == 0)
    int tbase = mbase & (T_SEQ - 1);
    u16* Vw = Vb + (size_t)(bb * NHEAD + hh) * HDIM * T_SEQ;
#pragma unroll
    for (int mi = 0; mi < 4; mi++)
#pragma unroll
      for (int r = 0; r < 4; r++) {
        int t = tbase + mi * 16 + quad * 4 + r;
#pragma unroll
        for (int ni = 0; ni < 4; ni++) {
          int d = ni * 16 + l15;
          ((__bf16*)Vw)[(size_t)d * T_SEQ + t] = (__bf16)(acc[mi][ni][r] + bvv[ni]);
        }
      }
  }
}

// Output projection: ctx bf16 @ Wo^T + bo -> f32 d_out. 64x64 tiles, grid
// (16, 64) = 1024 blocks = 4 blocks/CU (LDS 16 KB): four independent blocks
// per CU stagger barrier drains. Wave-tile 32x32, BK=64 plane staging.
__global__ __launch_bounds__(256) void k_gemm_out(
    const u16* __restrict__ ctx, const u16* __restrict__ Wot,
    const float* __restrict__ bo, float* __restrict__ Cout) {
  __shared__ __align__(16) u16 sA[64 * 64];
  __shared__ __align__(16) u16 sB[64 * 64];
  const int K = D_MODEL;
  int m0 = blockIdx.y * 64, n0 = blockIdx.x * 64;
  int tid = threadIdx.x, lane = tid & 63, wave = tid >> 6;
  int l15 = lane & 15, quad = lane >> 4;
  int wm = (wave >> 1) * 32, wn = (wave & 1) * 32;
  int r0 = tid >> 2, pcol0 = (tid & 3) * 8;
  const u16* A0 = ctx + (size_t)(m0 + r0) * K + pcol0;
  const u16* B0 = Wot + (size_t)(n0 + r0) * K + pcol0;
  u16* dA = sA + wave * 512; // one call = one full 64x32 plane (256 thr)
  u16* dB = sB + wave * 512;
  f32x4 acc[2][2] = {};
  for (int k0 = 0; k0 < K; k0 += 64) {
    __syncthreads(); // previous iter's frag reads done
    gl2lds16(A0 + k0, dA);
    gl2lds16(A0 + k0 + 32, dA + 2048); // plane1
    gl2lds16(B0 + k0, dB);
    gl2lds16(B0 + k0 + 32, dB + 2048);
    __syncthreads(); // barrier drain -> LDS data visible
#pragma unroll
    for (int kh = 0; kh < 2; kh++) {
      bf8v af[2], bf[2];
#pragma unroll
      for (int i = 0; i < 2; i++)
        af[i] = *(const bf8v*)(sA + kh * 2048 + (wm + i * 16 + l15) * 32 + quad * 8);
#pragma unroll
      for (int i = 0; i < 2; i++)
        bf[i] = *(const bf8v*)(sB + kh * 2048 + (wn + i * 16 + l15) * 32 + quad * 8);
#pragma unroll
      for (int mi = 0; mi < 2; mi++)
#pragma unroll
        for (int ni = 0; ni < 2; ni++)
          acc[mi][ni] = __builtin_amdgcn_mfma_f32_16x16x32_bf16(
              af[mi], bf[ni], acc[mi][ni], 0, 0, 0);
    }
  }
  float bvv[2];
#pragma unroll
  for (int ni = 0; ni < 2; ni++) bvv[ni] = bo[n0 + wn + ni * 16 + l15];
#pragma unroll
  for (int mi = 0; mi < 2; mi++)
#pragma unroll
    for (int r = 0; r < 4; r++) {
      size_t ro = (size_t)(m0 + wm + mi * 16 + quad * 4 + r) * D_MODEL + n0 + wn;
#pragma unroll
      for (int ni = 0; ni < 2; ni++)
        Cout[ro + ni * 16 + l15] = acc[mi][ni][r] + bvv[ni];
    }
}

// ---------------------------------------------------------------------------
// Flash attention v8: grid (T/128, B*H), 512 thr = 8 waves. Wave w: q sub-tile
// qw = w&3 (32 rows), key half kh = w>>2 (keys [kh*32, kh*32+32) of each
// 64-key tile). exp2-native softmax without max-subtraction => key halves
// accumulate independent unnormalized (O, l), merged once at the end via LDS.
// K/V double-buffered via global_load_lds DMA, ONE __syncthreads per tile.
// XOR-chunk swizzle (pc = gc ^ (row&7)). S^T = K@Q^T -> per-lane softmax.
// Per-g P round-trip (g1's score VALU issues under g0's PV MFMAs).
__global__ __launch_bounds__(512, 4) void k_attn(
    const u16* __restrict__ Qr, const u16* __restrict__ Kr,
    const u16* __restrict__ Vb, const float* __restrict__ frac,
    const float* __restrict__ alpha_pos, const float* __restrict__ alpha_neg,
    u16* __restrict__ ctx) {
  // smem carve (u16 elems):
  //   [0,8192)      kT[2][4096]  swizzled [key][d]
  //   [8192,16384)  vT[2][4096]  swizzled [d][key]
  //   [16384,26624) pT: 8 waves x 2 g x (16 q x 40)   (stride 40 = 80 B)
  // merge phase reuses [0,16896) as f32 O-scratch and tail as l-scratch.
  __shared__ __align__(16) u16 smem[26624];
  int bh = blockIdx.y, b = bh >> 4, h = bh & 15;
  int q0 = blockIdx.x * 128;
  int tid = threadIdx.x, wave = tid >> 6, lane = tid & 63;
  int l15 = lane & 15, quad = lane >> 4;
  int qw = wave & 3;  // q sub-tile (32 rows)
  int kh = wave >> 2; // key half within each 64-key tile

  const u16* Kh = Kr + (size_t)b * T_SEQ * D_MODEL + h * HDIM;
  const u16* Vh = Vb + (size_t)bh * HDIM * T_SEQ;
  const float* fb = frac + b * T_SEQ;

  // Q B-frags (B[k=d][n=q] = Q[q][d]): lane holds Q[q=l15][d=quad*8+j]
  bf8v qf[2][2];
  float fq[2];
#pragma unroll
  for (int g = 0; g < 2; g++) {
    int qrow = q0 + qw * 32 + g * 16 + l15;
    const u16* qbase =
        Qr + (size_t)(b * T_SEQ + qrow) * D_MODEL + h * HDIM + quad * 8;
    qf[g][0] = *(const bf8v*)qbase;
    qf[g][1] = *(const bf8v*)(qbase + 32);
    fq[g] = fb[qrow]; // S^T col = q = l15
  }
  // bias = ap*max(dd,0)+an*min(dd,0) = c1*dd + c2*|dd| (log2 domain)
  float ap = alpha_pos[h] * LOG2E, an = alpha_neg[h] * LOG2E;
  float c1 = 0.5f * (ap + an), c2 = 0.5f * (ap - an);
  bf8v onesv;
#pragma unroll
  for (int j = 0; j < 8; j++) onesv[j] = (__bf16)1.0f;
  f32x4 o[2][4] = {};
  f32x4 o_l[2] = {};
  u16* kT0 = smem;
  u16* vT0 = smem + 8192;
  u16* pw = smem + 16384 + wave * 1280; // 2 g x 640 elems

  // Hoisted frag offsets (elems). Swizzle: row r, chunk gc -> pc = gc^(r&7).
  int x0 = (quad ^ (l15 & 7)) * 8;
  int kidx[2], vidx[4];
#pragma unroll
  for (int nt = 0; nt < 2; nt++) // K rows kh*32 + nt*16 + l15
    kidx[nt] = (((kh * 2 + nt) * 16 + l15) << 6) + x0;
#pragma unroll
  for (int dt = 0; dt < 4; dt++) // V keys chunk quad + kh*4
    vidx[dt] = (((dt * 16 + l15) << 6) + x0) ^ (kh * 32);
  int pidx = l15 * 40 + quad * 8;

  // DMA staging map: 512 threads x 1 chunk per array per tile.
  // chunk p = tid; row = p>>3, pc = p&7; fetch global chunk gc = pc^(row&7).
  int kr0 = tid >> 3, gc0 = (tid & 7) ^ (kr0 & 7);
  const u16* kg0 = Kh + (size_t)kr0 * D_MODEL + gc0 * 8;
  const u16* vg0 = Vh + (size_t)kr0 * T_SEQ + gc0 * 8; // row = d here
  int woff = wave * 512; // wave-uniform LDS dest (elems); lane -> +lane*8

  auto stage = [&](int buf, int kbase) {
    gl2lds16(kg0 + (size_t)kbase * D_MODEL, kT0 + buf * 4096 + woff);
    gl2lds16(vg0 + kbase, vT0 + buf * 4096 + woff);
  };

  stage(0, 0);
  __syncthreads();

  for (int kt = 0; kt < T_SEQ / 64; kt++) {
    int kbase = kt * 64;
    int buf = kt & 1;
    if (kt + 1 < T_SEQ / 64) stage(buf ^ 1, kbase + 64);
    const u16* kb = kT0 + buf * 4096;
    const u16* vb = vT0 + buf * 4096;

    // K A-frags for this wave's key half: rows kh*32 + nt*16 + l15
    bf8v kf0[2], kf1[2];
#pragma unroll
    for (int nt = 0; nt < 2; nt++) {
      kf0[nt] = *(const bf8v*)(kb + kidx[nt]);
      kf1[nt] = *(const bf8v*)(kb + (kidx[nt] ^ 32));
    }
    // V B-frags: rows d = dt*16+l15; key chunks kh*4 + quad
    bf8v vf[4];
#pragma unroll
    for (int dt = 0; dt < 4; dt++) vf[dt] = *(const bf8v*)(vb + vidx[dt]);
    // frac[key] for this lane's 4 keys per nt (L1-resident)
    f32x4 fk4[2];
#pragma unroll
    for (int nt = 0; nt < 2; nt++)
      fk4[nt] = *(const f32x4*)(fb + kbase + kh * 32 + nt * 16 + quad * 4);

#pragma unroll
    for (int g = 0; g < 2; g++) {
      float fqg = fq[g];
      u16* pwg = pw + g * 640;
#pragma unroll
      for (int nt = 0; nt < 2; nt++) {
        // S^T tile: D[row=key_loc=nt*16+quad*4+r][col=q=l15], log2 domain
        f32x4 s = {};
        s = __builtin_amdgcn_mfma_f32_16x16x32_bf16(kf0[nt], qf[g][0], s, 0, 0, 0);
        s = __builtin_amdgcn_mfma_f32_16x16x32_bf16(kf1[nt], qf[g][1], s, 0, 0, 0);
        bf4v pk;
#pragma unroll
        for (int r = 0; r < 4; r++) {
          float dd = fk4[nt][r] - fqg;
          pk[r] = (__bf16)__builtin_amdgcn_exp2f(
              fmaf(c2, __builtin_fabsf(dd), fmaf(c1, dd, s[r])));
        }
        // P[q=l15][key_loc = nt*16 + quad*4 + r] -> one b64 write
        *(bf4v*)(pwg + l15 * 40 + nt * 16 + quad * 4) = pk;
      }
      asm volatile("s_waitcnt lgkmcnt(0)" ::: "memory"); // P visible to own wave
      // O_g += P_g @ V_half ; l_g += P_g @ ones. Drains while next g's score
      // VALU issues (separate pipes, same wave).
      bf8v pf = *(const bf8v*)(pwg + pidx);
      o_l[g] = __builtin_amdgcn_mfma_f32_16x16x32_bf16(pf, onesv, o_l[g], 0, 0, 0);
#pragma unroll
      for (int dt = 0; dt < 4; dt++)
        o[g][dt] = __builtin_amdgcn_mfma_f32_16x16x32_bf16(pf, vf[dt],
                                                           o[g][dt], 0, 0, 0);
    }
    __syncthreads(); // drains this iter's DMA (vmcnt) + frees cur buf
  }

  // ---- merge key halves. All KV/P LDS is dead past the loop's last barrier.
  // kh==1 waves publish (O,l); kh==0 waves combine, normalize, store.
  float* Of = (float*)smem;             // [128 q][66] f32 = 33792 B
  float* Lf = (float*)(smem + 26368);   // 128 f32 (tail of pT region)
  if (kh == 1) {
#pragma unroll
    for (int g = 0; g < 2; g++)
#pragma unroll
      for (int r = 0; r < 4; r++) {
        int ql = qw * 32 + g * 16 + quad * 4 + r;
#pragma unroll
        for (int dt = 0; dt < 4; dt++)
          Of[ql * 66 + dt * 16 + l15] = o[g][dt][r];
        if (l15 == 0) Lf[ql] = o_l[g][r];
      }
  }
  __syncthreads();
  if (kh == 0) {
#pragma unroll
    for (int g = 0; g < 2; g++)
#pragma unroll
      for (int r = 0; r < 4; r++) {
        int ql = qw * 32 + g * 16 + quad * 4 + r;
        float linv = 1.0f / (o_l[g][r] + Lf[ql]);
        __bf16* orow =
            (__bf16*)(ctx + (size_t)(b * T_SEQ + q0 + ql) * D_MODEL + h * HDIM);
#pragma unroll
        for (int dt = 0; dt < 4; dt++)
          orow[dt * 16 + l15] =
              (__bf16)((o[g][dt][r] + Of[ql * 66 + dt * 16 + l15]) * linv);
      }
  }
}

// ---------------------------------------------------------------------------
extern "C" void kernel_launch(void* const* d_in, const int* in_sizes, int n_in,
                              void* d_out, int out_size, void* d_ws,
                              size_t ws_size, hipStream_t stream) {
  const float* q = (const float*)d_in[0];
  const float* k = (const float*)d_in[1];
  const float* v = (const float*)d_in[2];
  const float* frac = (const float*)d_in[3];
  const float* Wq = (const float*)d_in[4];
  const float* Wk = (const float*)d_in[5];
  const float* Wv = (const float*)d_in[6];
  const float* Wo = (const float*)d_in[7];
  const float* bq = (const float*)d_in[8];
  const float* bk = (const float*)d_in[9];
  const float* bv = (const float*)d_in[10];
  const float* bo = (const float*)d_in[11];
  const float* alpha_pos = (const float*)d_in[12];
  const float* alpha_neg = (const float*)d_in[13];

  char* ws = (char*)d_ws;
  u16* Xb = (u16*)(ws + 0);
  u16* Wt = (u16*)(ws + 25165824);
  u16* Qr = (u16*)(ws + 33554432);
  u16* Kr = (u16*)(ws + 41943040);
  u16* Vtmp = (u16*)(ws + 50331648); // holds ctx
  u16* Vb = (u16*)(ws + 58720256);
  float* ctab = (float*)(ws + 67108864);
  float* stab = (float*)(ws + 67371008);
  u16* ctx = Vtmp;
  u16* QKVout = Qr; // Qr,Kr contiguous; z==2 writes Vb directly

  k_prep<<<dim3(7424), 256, 0, stream>>>(q, k, v, Wq, Wk, Wv, Wo, Xb, Wt, ctab,
                                         stab);
  k_gemm_qkv<<<dim3(8, 32, 3), 256, 0, stream>>>(Xb, Wt, bq, bk, bv, ctab, stab,
                                                 QKVout, Vb);
  k_attn<<<dim3(16, 32), 512, 0, stream>>>(Qr, Kr, Vb, frac, alpha_pos,
                                           alpha_neg, ctx);
  k_gemm_out<<<dim3(16, 64), 256, 0, stream>>>(ctx, Wt + 3 * 1048576, bo,
                                               (float*)d_out);
}

// Round 2
// 237.988 us; speedup vs baseline: 1.0762x; 1.0085x over previous
//
#include <hip/hip_runtime.h>

// ---------------------------------------------------------------------------
// CustomMultiHeadAttentionStoich: fused MHA with RoPE + frac-difference bias.
// B=2 T=2048 D_MODEL=1024 H=16 hd=64. All matmuls via mfma_f32_16x16x32_bf16.
//
// Verified gfx950 fragment layouts (learn_hip m89/m91, rounds 1-6 pass):
//   A-frag : lane holds A[m=lane&15][k=(lane>>4)*8 + j], j=0..7  (8 bf16, 16B)
//   B-frag : lane holds B[k=(lane>>4)*8 + j][n=lane&15]
//   C/D    : lane holds D[row=(lane>>4)*4 + r][col=lane&15], r=0..3 (4 f32)
//
// Round-9 changes (k_attn only; R8 post-mortem: occupancy doubled but
// VALUBusy stuck at 46% -> per-tile vmcnt(0) drain at __syncthreads is the
// stall; FETCH 70MB vs 25MB unique -> cross-XCD K/V re-fetch):
//  * 3-buffer K/V staging, raw s_barrier + counted s_waitcnt vmcnt(2)
//    (vmcnt(0) only on the last tile). Stage for tile t+2 issued at tile t
//    top -> every DMA has ~2 compute-tiles of slack; no full drain in loop.
//  * frac moved to LDS in prologue so in-loop vmcnt queue holds ONLY the
//    2 stage ops/tile (exact counted waits).
//  * XCD swizzle: all 16 q-blocks of a head -> same XCD (4 heads/XCD);
//    K/V become single-fetch L2 residents per XCD.
//  * s_setprio(1) around score + PV MFMA clusters.
//  LDS 76KB/block (3x16KB KV + 20KB P + 8KB frac) -> still 2 blocks/CU.
// ---------------------------------------------------------------------------

typedef unsigned short u16;
typedef __bf16 bf8v __attribute__((ext_vector_type(8)));
typedef __bf16 bf4v __attribute__((ext_vector_type(4)));
typedef float f32x4 __attribute__((ext_vector_type(4)));

#define D_MODEL 1024
#define T_SEQ   2048
#define NHEAD   16
#define HDIM    64
#define BATCH   2
#define M_TOT   (BATCH * T_SEQ) /* 4096 */
#define LOG2E   1.4426950408889634f

__device__ __forceinline__ void gl2lds16(const u16* g, u16* l) {
  __builtin_amdgcn_global_load_lds(
      (__attribute__((address_space(1))) void*)g,
      (__attribute__((address_space(3))) void*)l, 16, 0, 0);
}

// ---------------------------------------------------------------------------
// k_prep: zone-partitioned prep work in ONE launch.
//   blocks [0,6144)    : f32->bf16 convert of q/k/v into Xb
//   blocks [6144,7168) : W^T bf16 transpose of Wq/Wk/Wv/Wo into WtB
//   blocks [7168,7424) : RoPE cos/sin table
__global__ __launch_bounds__(256) void k_prep(
    const float* __restrict__ q, const float* __restrict__ k,
    const float* __restrict__ v, const float* __restrict__ Wq,
    const float* __restrict__ Wk, const float* __restrict__ Wv,
    const float* __restrict__ Wo, u16* __restrict__ Xb, u16* __restrict__ WtB,
    float* __restrict__ ct, float* __restrict__ st) {
  __shared__ float tile[64 * 65];
  int bx = blockIdx.x, tid = threadIdx.x;
  if (bx < 6144) { // ---- convert zone
    int z = bx >> 11, xb = bx & 2047;
    const float* src = (z == 0) ? q : (z == 1) ? k : v;
    u16* dst = Xb + (size_t)z * (M_TOT * D_MODEL);
    int idx = (xb * 256 + tid) * 8;
    float4 a = *(const float4*)(src + idx);
    float4 b = *(const float4*)(src + idx + 4);
    bf8v o;
    o[0] = (__bf16)a.x; o[1] = (__bf16)a.y; o[2] = (__bf16)a.z; o[3] = (__bf16)a.w;
    o[4] = (__bf16)b.x; o[5] = (__bf16)b.y; o[6] = (__bf16)b.z; o[7] = (__bf16)b.w;
    *(bf8v*)(dst + idx) = o;
  } else if (bx < 7168) { // ---- W transpose zone (64x64 tiles, stride 65)
    int idx2 = bx - 6144;
    int z = idx2 >> 8, rem = idx2 & 255;
    int k0 = (rem >> 4) * 64, n0 = (rem & 15) * 64;
    const float* W = (z == 0) ? Wq : (z == 1) ? Wk : (z == 2) ? Wv : Wo;
    u16* Wt = WtB + (size_t)z * (D_MODEL * D_MODEL);
#pragma unroll
    for (int i = 0; i < 16; i++) {
      int idx = tid + i * 256;
      int r = idx >> 6, c = idx & 63;
      tile[c * 65 + r] = W[(size_t)(k0 + r) * D_MODEL + n0 + c];
    }
    __syncthreads();
#pragma unroll
    for (int i = 0; i < 16; i++) {
      int idx = tid + i * 256;
      int r = idx >> 6, c = idx & 63;
      ((__bf16*)Wt)[(size_t)(n0 + r) * D_MODEL + k0 + c] = (__bf16)tile[r * 65 + c];
    }
  } else { // ---- RoPE table zone: angle(t,d) = t / 10000^(d/32)
    int idx = (bx - 7168) * 256 + tid; // = t*32 + d
    int t = idx >> 5, d = idx & 31;
    float ang = (float)t * powf(10000.0f, -(float)d * (1.0f / 32.0f));
    ct[idx] = cosf(ang);
    st[idx] = sinf(ang);
  }
}

// ---------------------------------------------------------------------------
// QKV GEMM core (r4/r6 structure): C = A[M][K] @ Bt[N][K]^T, K=1024, BK=64
// (two stride-32 planes per operand, bank-balanced b128 frag reads).
// 2-barrier single-buffer global_load_lds staging. BM=128, BN=128.
__device__ __forceinline__ void gemm_core_128(const u16* __restrict__ A,
                                              const u16* __restrict__ Bt,
                                              u16* sA, u16* sB,
                                              f32x4 (&acc)[4][4],
                                              int m0, int n0) {
  const int K = D_MODEL;
  int tid = threadIdx.x;
  int lane = tid & 63, wave = tid >> 6;
  int l15 = lane & 15, quad = lane >> 4;
  int wm = (wave >> 1) * 64, wn = (wave & 1) * 64;
  int r0 = tid >> 2, pcol0 = (tid & 3) * 8;
  int r1 = 64 + r0;
  const u16* A0 = A + (size_t)(m0 + r0) * K + pcol0;
  const u16* A1 = A + (size_t)(m0 + r1) * K + pcol0;
  const u16* B0 = Bt + (size_t)(n0 + r0) * K + pcol0;
  const u16* B1 = Bt + (size_t)(n0 + r1) * K + pcol0;
  u16* dA0 = sA + wave * 512;        // plane0, rows 0..63 (wave-uniform base)
  u16* dA1 = sA + 2048 + wave * 512; // plane0, rows 64..127
  u16* dB0 = sB + wave * 512;
  u16* dB1 = sB + 2048 + wave * 512;
  for (int k0 = 0; k0 < K; k0 += 64) {
    __syncthreads(); // previous iter's frag reads done
    gl2lds16(A0 + k0, dA0);
    gl2lds16(A1 + k0, dA1);
    gl2lds16(A0 + k0 + 32, dA0 + 4096); // plane1
    gl2lds16(A1 + k0 + 32, dA1 + 4096);
    gl2lds16(B0 + k0, dB0);
    gl2lds16(B0 + k0 + 32, dB0 + 4096);
    gl2lds16(B1 + k0, dB1);
    gl2lds16(B1 + k0 + 32, dB1 + 4096);
    __syncthreads(); // barrier drain -> LDS data visible
#pragma unroll
    for (int kh = 0; kh < 2; kh++) {
      bf8v af[4], bf[4];
#pragma unroll
      for (int i = 0; i < 4; i++)
        af[i] = *(const bf8v*)(sA + kh * 4096 + (wm + i * 16 + l15) * 32 + quad * 8);
#pragma unroll
      for (int i = 0; i < 4; i++)
        bf[i] = *(const bf8v*)(sB + kh * 4096 + (wn + i * 16 + l15) * 32 + quad * 8);
#pragma unroll
      for (int mi = 0; mi < 4; mi++)
#pragma unroll
        for (int ni = 0; ni < 4; ni++)
          acc[mi][ni] = __builtin_amdgcn_mfma_f32_16x16x32_bf16(
              af[mi], bf[ni], acc[mi][ni], 0, 0, 0);
    }
  }
}

// QKV projection, grid (8, 32, 3). z<2 -> RoPE fused; z==0 prescales Q by
// 0.125*log2e. z==2 writes projected V DIRECTLY TRANSPOSED into Vb[b][h][d][t].
__global__ __launch_bounds__(256) void k_gemm_qkv(
    const u16* __restrict__ Xb, const u16* __restrict__ WtB,
    const float* __restrict__ bq, const float* __restrict__ bk,
    const float* __restrict__ bv, const float* __restrict__ ctab,
    const float* __restrict__ stab, u16* __restrict__ OutB,
    u16* __restrict__ Vb) {
  __shared__ __align__(16) u16 sA[128 * 64];
  __shared__ __align__(16) u16 sB[128 * 64];
  int z = blockIdx.z;
  const u16* A = Xb + (size_t)z * (M_TOT * D_MODEL);
  const u16* Bt = WtB + (size_t)z * (D_MODEL * D_MODEL);
  const float* bias = (z == 0) ? bq : (z == 1) ? bk : bv;
  u16* Out = OutB + (size_t)z * (M_TOT * D_MODEL);
  int m0 = blockIdx.y * 128, n0 = blockIdx.x * 128;
  f32x4 acc[4][4] = {};
  gemm_core_128(A, Bt, sA, sB, acc, m0, n0);

  int tid = threadIdx.x, lane = tid & 63, wave = tid >> 6;
  int l15 = lane & 15, quad = lane >> 4;
  int wm = (wave >> 1) * 64, wn = (wave & 1) * 64;
  float bvv[4];
#pragma unroll
  for (int ni = 0; ni < 4; ni++) bvv[ni] = bias[n0 + wn + ni * 16 + l15];

  if (z < 2) { // Q/K: RoPE fused; Q also prescaled 0.125*log2e
    float qs = (z == 0) ? 0.125f * LOG2E : 1.0f;
#pragma unroll
    for (int mi = 0; mi < 4; mi++) {
#pragma unroll
      for (int r = 0; r < 4; r++) {
        int m = m0 + wm + mi * 16 + quad * 4 + r; // global row = b*T + t
        size_t ro = (size_t)m * D_MODEL + n0 + wn;
        int tl = m & (T_SEQ - 1);
#pragma unroll
        for (int ni = 0; ni < 2; ni++) {
          int d = ni * 16 + l15; // < 32; pair (d, d+32) in regs ni, ni+2
          float c = ctab[tl * 32 + d], s = stab[tl * 32 + d];
          float xl = acc[mi][ni][r] + bvv[ni];
          float xr = acc[mi][ni + 2][r] + bvv[ni + 2];
          ((__bf16*)Out)[ro + d] = (__bf16)((xl * c - xr * s) * qs);
          ((__bf16*)Out)[ro + d + 32] = (__bf16)((xl * s + xr * c) * qs);
        }
      }
    }
  } else { // V: write transposed Vb[b][h][d][t] (wave's 64 cols = one head)
    int hh = (n0 + wn) >> 6;
    int mbase = m0 + wm;
    int bb = mbase >> 11; // tile never crosses batch (2048 % 128 == 0)
    int tbase = mbase & (T_SEQ - 1);
    u16* Vw = Vb + (size_t)(bb * NHEAD + hh) * HDIM * T_SEQ;
#pragma unroll
    for (int mi = 0; mi < 4; mi++)
#pragma unroll
      for (int r = 0; r < 4; r++) {
        int t = tbase + mi * 16 + quad * 4 + r;
#pragma unroll
        for (int ni = 0; ni < 4; ni++) {
          int d = ni * 16 + l15;
          ((__bf16*)Vw)[(size_t)d * T_SEQ + t] = (__bf16)(acc[mi][ni][r] + bvv[ni]);
        }
      }
  }
}

// Output projection: ctx bf16 @ Wo^T + bo -> f32 d_out. 64x64 tiles, grid
// (16, 64) = 1024 blocks = 4 blocks/CU (LDS 16 KB): four independent blocks
// per CU stagger barrier drains. Wave-tile 32x32, BK=64 plane staging.
__global__ __launch_bounds__(256) void k_gemm_out(
    const u16* __restrict__ ctx, const u16* __restrict__ Wot,
    const float* __restrict__ bo, float* __restrict__ Cout) {
  __shared__ __align__(16) u16 sA[64 * 64];
  __shared__ __align__(16) u16 sB[64 * 64];
  const int K = D_MODEL;
  int m0 = blockIdx.y * 64, n0 = blockIdx.x * 64;
  int tid = threadIdx.x, lane = tid & 63, wave = tid >> 6;
  int l15 = lane & 15, quad = lane >> 4;
  int wm = (wave >> 1) * 32, wn = (wave & 1) * 32;
  int r0 = tid >> 2, pcol0 = (tid & 3) * 8;
  const u16* A0 = ctx + (size_t)(m0 + r0) * K + pcol0;
  const u16* B0 = Wot + (size_t)(n0 + r0) * K + pcol0;
  u16* dA = sA + wave * 512; // one call = one full 64x32 plane (256 thr)
  u16* dB = sB + wave * 512;
  f32x4 acc[2][2] = {};
  for (int k0 = 0; k0 < K; k0 += 64) {
    __syncthreads(); // previous iter's frag reads done
    gl2lds16(A0 + k0, dA);
    gl2lds16(A0 + k0 + 32, dA + 2048); // plane1
    gl2lds16(B0 + k0, dB);
    gl2lds16(B0 + k0 + 32, dB + 2048);
    __syncthreads(); // barrier drain -> LDS data visible
#pragma unroll
    for (int kh = 0; kh < 2; kh++) {
      bf8v af[2], bf[2];
#pragma unroll
      for (int i = 0; i < 2; i++)
        af[i] = *(const bf8v*)(sA + kh * 2048 + (wm + i * 16 + l15) * 32 + quad * 8);
#pragma unroll
      for (int i = 0; i < 2; i++)
        bf[i] = *(const bf8v*)(sB + kh * 2048 + (wn + i * 16 + l15) * 32 + quad * 8);
#pragma unroll
      for (int mi = 0; mi < 2; mi++)
#pragma unroll
        for (int ni = 0; ni < 2; ni++)
          acc[mi][ni] = __builtin_amdgcn_mfma_f32_16x16x32_bf16(
              af[mi], bf[ni], acc[mi][ni], 0, 0, 0);
    }
  }
  float bvv[2];
#pragma unroll
  for (int ni = 0; ni < 2; ni++) bvv[ni] = bo[n0 + wn + ni * 16 + l15];
#pragma unroll
  for (int mi = 0; mi < 2; mi++)
#pragma unroll
    for (int r = 0; r < 4; r++) {
      size_t ro = (size_t)(m0 + wm + mi * 16 + quad * 4 + r) * D_MODEL + n0 + wn;
#pragma unroll
      for (int ni = 0; ni < 2; ni++)
        Cout[ro + ni * 16 + l15] = acc[mi][ni][r] + bvv[ni];
    }
}

// ---------------------------------------------------------------------------
// Flash attention v9: grid (T/128, B*H) XCD-swizzled, 512 thr = 8 waves.
// Wave w: q sub-tile qw = w&3 (32 rows), key half kh = w>>2. exp2-native
// softmax without max-subtraction => key halves accumulate independent
// unnormalized (O, l), merged once at the end via LDS.
// K/V TRIPLE-buffered global_load_lds DMA, raw s_barrier + counted vmcnt(2)
// (stage for tile t+2 issued at tile t; no vmcnt(0) drain in loop). frac
// staged to LDS in prologue so the vmcnt queue holds only stage ops.
__global__ __launch_bounds__(512, 4) void k_attn(
    const u16* __restrict__ Qr, const u16* __restrict__ Kr,
    const u16* __restrict__ Vb, const float* __restrict__ frac,
    const float* __restrict__ alpha_pos, const float* __restrict__ alpha_neg,
    u16* __restrict__ ctx) {
  // smem carve (u16 elems):
  //   [0,12288)      kT[3][4096]  swizzled [key][d]
  //   [12288,24576)  vT[3][4096]  swizzled [d][key]
  //   [24576,34816)  pT: 8 waves x 2 g x (16 q x 40)  (stride 40 = 80 B)
  //   [34816,38912)  fLds: f32[2048] frac row for this batch
  // merge phase reuses [0,16896) as f32 O-scratch, [16896,17152) l-scratch.
  __shared__ __align__(16) u16 smem[38912];
  // ---- XCD swizzle: lin%8 = XCD (round-robin). Give each XCD 4 whole heads
  // so all 16 q-blocks of a head share one L2 (K/V single-fetch per XCD).
  int lin = blockIdx.x + (blockIdx.y << 4);
  int xcd = lin & 7, slot = lin >> 3;
  int bh = (xcd << 2) | (slot >> 4);
  int q0 = (slot & 15) << 7;
  int b = bh >> 4, h = bh & 15;
  int tid = threadIdx.x, wave = tid >> 6, lane = tid & 63;
  int l15 = lane & 15, quad = lane >> 4;
  int qw = wave & 3;  // q sub-tile (32 rows)
  int kh = wave >> 2; // key half within each 64-key tile

  const u16* Kh = Kr + (size_t)b * T_SEQ * D_MODEL + h * HDIM;
  const u16* Vh = Vb + (size_t)bh * HDIM * T_SEQ;
  const float* fb = frac + b * T_SEQ;

  u16* kT0 = smem;
  u16* vT0 = smem + 12288;
  u16* pw = smem + 24576 + wave * 1280; // 2 g x 640 elems
  float* fl = (float*)(smem + 34816);

  // Q B-frags (B[k=d][n=q] = Q[q][d]): lane holds Q[q=l15][d=quad*8+j]
  bf8v qf[2][2];
  float fq[2];
#pragma unroll
  for (int g = 0; g < 2; g++) {
    int qrow = q0 + qw * 32 + g * 16 + l15;
    const u16* qbase =
        Qr + (size_t)(b * T_SEQ + qrow) * D_MODEL + h * HDIM + quad * 8;
    qf[g][0] = *(const bf8v*)qbase;
    qf[g][1] = *(const bf8v*)(qbase + 32);
    fq[g] = fb[qrow]; // S^T col = q = l15
  }
  // frac -> LDS (512 thr x 4 floats = 2048). Compiler waits the global load
  // before the ds_write; stages below are issued after -> clean vmcnt queue.
  {
    f32x4 fv = *(const f32x4*)(fb + (tid << 2));
    *(f32x4*)(fl + (tid << 2)) = fv;
  }

  // bias = ap*max(dd,0)+an*min(dd,0) = c1*dd + c2*|dd| (log2 domain)
  float ap = alpha_pos[h] * LOG2E, an = alpha_neg[h] * LOG2E;
  float c1 = 0.5f * (ap + an), c2 = 0.5f * (ap - an);
  bf8v onesv;
#pragma unroll
  for (int j = 0; j < 8; j++) onesv[j] = (__bf16)1.0f;
  f32x4 o[2][4] = {};
  f32x4 o_l[2] = {};

  // Hoisted frag offsets (elems). Swizzle: row r, chunk gc -> pc = gc^(r&7).
  int x0 = (quad ^ (l15 & 7)) * 8;
  int kidx[2], vidx[4];
#pragma unroll
  for (int nt = 0; nt < 2; nt++) // K rows kh*32 + nt*16 + l15
    kidx[nt] = (((kh * 2 + nt) * 16 + l15) << 6) + x0;
#pragma unroll
  for (int dt = 0; dt < 4; dt++) // V keys chunk quad + kh*4
    vidx[dt] = (((dt * 16 + l15) << 6) + x0) ^ (kh * 32);
  int pidx = l15 * 40 + quad * 8;

  // DMA staging map: 512 threads x 1 chunk per array per tile.
  // chunk p = tid; row = p>>3, pc = p&7; fetch global chunk gc = pc^(row&7).
  int kr0 = tid >> 3, gc0 = (tid & 7) ^ (kr0 & 7);
  const u16* kg0 = Kh + (size_t)kr0 * D_MODEL + gc0 * 8;
  const u16* vg0 = Vh + (size_t)kr0 * T_SEQ + gc0 * 8; // row = d here
  int woff = wave * 512; // wave-uniform LDS dest (elems); lane -> +lane*8

  auto stage = [&](int bufoff, int kbase) {
    gl2lds16(kg0 + (size_t)kbase * D_MODEL, kT0 + bufoff + woff);
    gl2lds16(vg0 + kbase, vT0 + bufoff + woff);
  };

  stage(0, 0);
  stage(4096, 64);
  asm volatile("s_waitcnt lgkmcnt(0)" ::: "memory"); // fLds writes committed

  int oc = 0, o1 = 4096, o2 = 8192; // rotating buffer offsets
  for (int kt = 0; kt < T_SEQ / 64; kt++) {
    int kbase = kt * 64;
    // counted wait: own stage(kt) landed (2 newest = stage(kt+1) may fly)
    if (kt == T_SEQ / 64 - 1)
      asm volatile("s_waitcnt vmcnt(0)" ::: "memory");
    else
      asm volatile("s_waitcnt vmcnt(2)" ::: "memory");
    __builtin_amdgcn_s_barrier(); // all waves' stage(kt) landed; all waves
                                  // done reading buf o2 (tile kt-1)
    asm volatile("" ::: "memory");
    __builtin_amdgcn_sched_barrier(0);
    if (kt + 2 < T_SEQ / 64) stage(o2, kbase + 128);
    const u16* kb = kT0 + oc;
    const u16* vb = vT0 + oc;

    // K A-frags for this wave's key half: rows kh*32 + nt*16 + l15
    bf8v kf0[2], kf1[2];
#pragma unroll
    for (int nt = 0; nt < 2; nt++) {
      kf0[nt] = *(const bf8v*)(kb + kidx[nt]);
      kf1[nt] = *(const bf8v*)(kb + (kidx[nt] ^ 32));
    }
    // V B-frags: rows d = dt*16+l15; key chunks kh*4 + quad
    bf8v vf[4];
#pragma unroll
    for (int dt = 0; dt < 4; dt++) vf[dt] = *(const bf8v*)(vb + vidx[dt]);
    // frac[key] for this lane's 4 keys per nt (LDS, 16-lane broadcast)
    f32x4 fk4[2];
#pragma unroll
    for (int nt = 0; nt < 2; nt++)
      fk4[nt] = *(const f32x4*)(fl + kbase + kh * 32 + nt * 16 + quad * 4);

#pragma unroll
    for (int g = 0; g < 2; g++) {
      float fqg = fq[g];
      u16* pwg = pw + g * 640;
#pragma unroll
      for (int nt = 0; nt < 2; nt++) {
        // S^T tile: D[row=key_loc=nt*16+quad*4+r][col=q=l15], log2 domain
        f32x4 s = {};
        __builtin_amdgcn_s_setprio(1);
        s = __builtin_amdgcn_mfma_f32_16x16x32_bf16(kf0[nt], qf[g][0], s, 0, 0, 0);
        s = __builtin_amdgcn_mfma_f32_16x16x32_bf16(kf1[nt], qf[g][1], s, 0, 0, 0);
        __builtin_amdgcn_s_setprio(0);
        bf4v pk;
#pragma unroll
        for (int r = 0; r < 4; r++) {
          float dd = fk4[nt][r] - fqg;
          pk[r] = (__bf16)__builtin_amdgcn_exp2f(
              fmaf(c2, __builtin_fabsf(dd), fmaf(c1, dd, s[r])));
        }
        // P[q=l15][key_loc = nt*16 + quad*4 + r] -> one b64 write
        *(bf4v*)(pwg + l15 * 40 + nt * 16 + quad * 4) = pk;
      }
      asm volatile("s_waitcnt lgkmcnt(0)" ::: "memory"); // P visible to own wave
      // O_g += P_g @ V_half ; l_g += P_g @ ones. Drains while next g's score
      // VALU issues (separate pipes, same wave).
      bf8v pf = *(const bf8v*)(pwg + pidx);
      __builtin_amdgcn_s_setprio(1);
      o_l[g] = __builtin_amdgcn_mfma_f32_16x16x32_bf16(pf, onesv, o_l[g], 0, 0, 0);
#pragma unroll
      for (int dt = 0; dt < 4; dt++)
        o[g][dt] = __builtin_amdgcn_mfma_f32_16x16x32_bf16(pf, vf[dt],
                                                           o[g][dt], 0, 0, 0);
      __builtin_amdgcn_s_setprio(0);
    }
    int tmp = oc; oc = o1; o1 = o2; o2 = tmp; // rotate buffers
  }
  __syncthreads(); // last tile's frag reads done -> smem reusable

  // ---- merge key halves. kh==1 waves publish (O,l); kh==0 combine+store.
  float* Of = (float*)smem;             // [128 q][66] f32 = 33792 B
  float* Lf = (float*)(smem + 16896);   // 128 f32
  if (kh == 1) {
#pragma unroll
    for (int g = 0; g < 2; g++)
#pragma unroll
      for (int r = 0; r < 4; r++) {
        int ql = qw * 32 + g * 16 + quad * 4 + r;
#pragma unroll
        for (int dt = 0; dt < 4; dt++)
          Of[ql * 66 + dt * 16 + l15] = o[g][dt][r];
        if (l15 == 0) Lf[ql] = o_l[g][r];
      }
  }
  __syncthreads();
  if (kh == 0) {
#pragma unroll
    for (int g = 0; g < 2; g++)
#pragma unroll
      for (int r = 0; r < 4; r++) {
        int ql = qw * 32 + g * 16 + quad * 4 + r;
        float linv = 1.0f / (o_l[g][r] + Lf[ql]);
        __bf16* orow =
            (__bf16*)(ctx + (size_t)(b * T_SEQ + q0 + ql) * D_MODEL + h * HDIM);
#pragma unroll
        for (int dt = 0; dt < 4; dt++)
          orow[dt * 16 + l15] =
              (__bf16)((o[g][dt][r] + Of[ql * 66 + dt * 16 + l15]) * linv);
      }
  }
}

// ---------------------------------------------------------------------------
extern "C" void kernel_launch(void* const* d_in, const int* in_sizes, int n_in,
                              void* d_out, int out_size, void* d_ws,
                              size_t ws_size, hipStream_t stream) {
  const float* q = (const float*)d_in[0];
  const float* k = (const float*)d_in[1];
  const float* v = (const float*)d_in[2];
  const float* frac = (const float*)d_in[3];
  const float* Wq = (const float*)d_in[4];
  const float* Wk = (const float*)d_in[5];
  const float* Wv = (const float*)d_in[6];
  const float* Wo = (const float*)d_in[7];
  const float* bq = (const float*)d_in[8];
  const float* bk = (const float*)d_in[9];
  const float* bv = (const float*)d_in[10];
  const float* bo = (const float*)d_in[11];
  const float* alpha_pos = (const float*)d_in[12];
  const float* alpha_neg = (const float*)d_in[13];

  char* ws = (char*)d_ws;
  u16* Xb = (u16*)(ws + 0);
  u16* Wt = (u16*)(ws + 25165824);
  u16* Qr = (u16*)(ws + 33554432);
  u16* Kr = (u16*)(ws + 41943040);
  u16* Vtmp = (u16*)(ws + 50331648); // holds ctx
  u16* Vb = (u16*)(ws + 58720256);
  float* ctab = (float*)(ws + 67108864);
  float* stab = (float*)(ws + 67371008);
  u16* ctx = Vtmp;
  u16* QKVout = Qr; // Qr,Kr contiguous; z==2 writes Vb directly

  k_prep<<<dim3(7424), 256, 0, stream>>>(q, k, v, Wq, Wk, Wv, Wo, Xb, Wt, ctab,
                                         stab);
  k_gemm_qkv<<<dim3(8, 32, 3), 256, 0, stream>>>(Xb, Wt, bq, bk, bv, ctab, stab,
                                                 QKVout, Vb);
  k_attn<<<dim3(16, 32), 512, 0, stream>>>(Qr, Kr, Vb, frac, alpha_pos,
                                           alpha_neg, ctx);
  k_gemm_out<<<dim3(16, 64), 256, 0, stream>>>(ctx, Wt + 3 * 1048576, bo,
                                               (float*)d_out);
}

// Round 3
// 231.633 us; speedup vs baseline: 1.1057x; 1.0274x over previous
//
#include <hip/hip_runtime.h>

// ---------------------------------------------------------------------------
// CustomMultiHeadAttentionStoich: fused MHA with RoPE + frac-difference bias.
// B=2 T=2048 D_MODEL=1024 H=16 hd=64. All matmuls via mfma_f32_16x16x32_bf16.
//
// Verified gfx950 fragment layouts (learn_hip m89/m91, rounds 1-6 pass):
//   A-frag : lane holds A[m=lane&15][k=(lane>>4)*8 + j], j=0..7  (8 bf16, 16B)
//   B-frag : lane holds B[k=(lane>>4)*8 + j][n=lane&15]
//   C/D    : lane holds D[row=(lane>>4)*4 + r][col=lane&15], r=0..3 (4 f32)
//
// Round-10 changes (k_attn only). R9 post-mortem: counted-vmcnt/3-buf was a
// NULL (not drain-bound); LDS pipe ~70% busy and the 3.4M bank conflicts are
// the stride-40 P round-trip (even-banks-only). So:
//  * P LDS round-trip ELIMINATED: in-register transpose via
//    v_cvt_pk_bf16_f32 + v_permlane32_swap_b32 + v_permlane16_swap_b32.
//    Lane(l15,q) holds keys {4q..4q+3}u{16+4q..+3} after S^T; swaps on word
//    pairs (A0,B0),(A1,B1) produce the PV A-frag words {8q..8q+7} directly.
//    Removes 6 LDS ops + 2 lgkmcnt(0) serializations per tile per wave,
//    all P bank conflicts, and 20 KB LDS.
//  * Reverted R9 regressors: back to 2-buffer KV + single __syncthreads
//    (R8 structure); no sched_barrier(0), no setprio, no counted vmcnt.
//  * Kept: XCD swizzle (FETCH 70->13 MB), frac in LDS, c1/c2 bias form.
//  * Persistent zero4 for S-init (kills 16 v_mov/tile).
//  LDS 40 KB (kT[2]+vT[2]+frac); occupancy stays register-capped (~104/wave
//  incl. 40 AGPR acc -> 4 waves/SIMD).
// ---------------------------------------------------------------------------

typedef unsigned short u16;
typedef __bf16 bf8v __attribute__((ext_vector_type(8)));
typedef __bf16 bf4v __attribute__((ext_vector_type(4)));
typedef float f32x4 __attribute__((ext_vector_type(4)));
typedef unsigned int u32x4v __attribute__((ext_vector_type(4)));

#define D_MODEL 1024
#define T_SEQ   2048
#define NHEAD   16
#define HDIM    64
#define BATCH   2
#define M_TOT   (BATCH * T_SEQ) /* 4096 */
#define LOG2E   1.4426950408889634f

__device__ __forceinline__ void gl2lds16(const u16* g, u16* l) {
  __builtin_amdgcn_global_load_lds(
      (__attribute__((address_space(1))) void*)g,
      (__attribute__((address_space(3))) void*)l, 16, 0, 0);
}

// ---------------------------------------------------------------------------
// k_prep: zone-partitioned prep work in ONE launch.
//   blocks [0,6144)    : f32->bf16 convert of q/k/v into Xb
//   blocks [6144,7168) : W^T bf16 transpose of Wq/Wk/Wv/Wo into WtB
//   blocks [7168,7424) : RoPE cos/sin table
__global__ __launch_bounds__(256) void k_prep(
    const float* __restrict__ q, const float* __restrict__ k,
    const float* __restrict__ v, const float* __restrict__ Wq,
    const float* __restrict__ Wk, const float* __restrict__ Wv,
    const float* __restrict__ Wo, u16* __restrict__ Xb, u16* __restrict__ WtB,
    float* __restrict__ ct, float* __restrict__ st) {
  __shared__ float tile[64 * 65];
  int bx = blockIdx.x, tid = threadIdx.x;
  if (bx < 6144) { // ---- convert zone
    int z = bx >> 11, xb = bx & 2047;
    const float* src = (z == 0) ? q : (z == 1) ? k : v;
    u16* dst = Xb + (size_t)z * (M_TOT * D_MODEL);
    int idx = (xb * 256 + tid) * 8;
    float4 a = *(const float4*)(src + idx);
    float4 b = *(const float4*)(src + idx + 4);
    bf8v o;
    o[0] = (__bf16)a.x; o[1] = (__bf16)a.y; o[2] = (__bf16)a.z; o[3] = (__bf16)a.w;
    o[4] = (__bf16)b.x; o[5] = (__bf16)b.y; o[6] = (__bf16)b.z; o[7] = (__bf16)b.w;
    *(bf8v*)(dst + idx) = o;
  } else if (bx < 7168) { // ---- W transpose zone (64x64 tiles, stride 65)
    int idx2 = bx - 6144;
    int z = idx2 >> 8, rem = idx2 & 255;
    int k0 = (rem >> 4) * 64, n0 = (rem & 15) * 64;
    const float* W = (z == 0) ? Wq : (z == 1) ? Wk : (z == 2) ? Wv : Wo;
    u16* Wt = WtB + (size_t)z * (D_MODEL * D_MODEL);
#pragma unroll
    for (int i = 0; i < 16; i++) {
      int idx = tid + i * 256;
      int r = idx >> 6, c = idx & 63;
      tile[c * 65 + r] = W[(size_t)(k0 + r) * D_MODEL + n0 + c];
    }
    __syncthreads();
#pragma unroll
    for (int i = 0; i < 16; i++) {
      int idx = tid + i * 256;
      int r = idx >> 6, c = idx & 63;
      ((__bf16*)Wt)[(size_t)(n0 + r) * D_MODEL + k0 + c] = (__bf16)tile[r * 65 + c];
    }
  } else { // ---- RoPE table zone: angle(t,d) = t / 10000^(d/32)
    int idx = (bx - 7168) * 256 + tid; // = t*32 + d
    int t = idx >> 5, d = idx & 31;
    float ang = (float)t * powf(10000.0f, -(float)d * (1.0f / 32.0f));
    ct[idx] = cosf(ang);
    st[idx] = sinf(ang);
  }
}

// ---------------------------------------------------------------------------
// QKV GEMM core (r4/r6 structure): C = A[M][K] @ Bt[N][K]^T, K=1024, BK=64
// (two stride-32 planes per operand, bank-balanced b128 frag reads).
// 2-barrier single-buffer global_load_lds staging. BM=128, BN=128.
__device__ __forceinline__ void gemm_core_128(const u16* __restrict__ A,
                                              const u16* __restrict__ Bt,
                                              u16* sA, u16* sB,
                                              f32x4 (&acc)[4][4],
                                              int m0, int n0) {
  const int K = D_MODEL;
  int tid = threadIdx.x;
  int lane = tid & 63, wave = tid >> 6;
  int l15 = lane & 15, quad = lane >> 4;
  int wm = (wave >> 1) * 64, wn = (wave & 1) * 64;
  int r0 = tid >> 2, pcol0 = (tid & 3) * 8;
  int r1 = 64 + r0;
  const u16* A0 = A + (size_t)(m0 + r0) * K + pcol0;
  const u16* A1 = A + (size_t)(m0 + r1) * K + pcol0;
  const u16* B0 = Bt + (size_t)(n0 + r0) * K + pcol0;
  const u16* B1 = Bt + (size_t)(n0 + r1) * K + pcol0;
  u16* dA0 = sA + wave * 512;        // plane0, rows 0..63 (wave-uniform base)
  u16* dA1 = sA + 2048 + wave * 512; // plane0, rows 64..127
  u16* dB0 = sB + wave * 512;
  u16* dB1 = sB + 2048 + wave * 512;
  for (int k0 = 0; k0 < K; k0 += 64) {
    __syncthreads(); // previous iter's frag reads done
    gl2lds16(A0 + k0, dA0);
    gl2lds16(A1 + k0, dA1);
    gl2lds16(A0 + k0 + 32, dA0 + 4096); // plane1
    gl2lds16(A1 + k0 + 32, dA1 + 4096);
    gl2lds16(B0 + k0, dB0);
    gl2lds16(B0 + k0 + 32, dB0 + 4096);
    gl2lds16(B1 + k0, dB1);
    gl2lds16(B1 + k0 + 32, dB1 + 4096);
    __syncthreads(); // barrier drain -> LDS data visible
#pragma unroll
    for (int kh = 0; kh < 2; kh++) {
      bf8v af[4], bf[4];
#pragma unroll
      for (int i = 0; i < 4; i++)
        af[i] = *(const bf8v*)(sA + kh * 4096 + (wm + i * 16 + l15) * 32 + quad * 8);
#pragma unroll
      for (int i = 0; i < 4; i++)
        bf[i] = *(const bf8v*)(sB + kh * 4096 + (wn + i * 16 + l15) * 32 + quad * 8);
#pragma unroll
      for (int mi = 0; mi < 4; mi++)
#pragma unroll
        for (int ni = 0; ni < 4; ni++)
          acc[mi][ni] = __builtin_amdgcn_mfma_f32_16x16x32_bf16(
              af[mi], bf[ni], acc[mi][ni], 0, 0, 0);
    }
  }
}

// QKV projection, grid (8, 32, 3). z<2 -> RoPE fused; z==0 prescales Q by
// 0.125*log2e. z==2 writes projected V DIRECTLY TRANSPOSED into Vb[b][h][d][t].
__global__ __launch_bounds__(256) void k_gemm_qkv(
    const u16* __restrict__ Xb, const u16* __restrict__ WtB,
    const float* __restrict__ bq, const float* __restrict__ bk,
    const float* __restrict__ bv, const float* __restrict__ ctab,
    const float* __restrict__ stab, u16* __restrict__ OutB,
    u16* __restrict__ Vb) {
  __shared__ __align__(16) u16 sA[128 * 64];
  __shared__ __align__(16) u16 sB[128 * 64];
  int z = blockIdx.z;
  const u16* A = Xb + (size_t)z * (M_TOT * D_MODEL);
  const u16* Bt = WtB + (size_t)z * (D_MODEL * D_MODEL);
  const float* bias = (z == 0) ? bq : (z == 1) ? bk : bv;
  u16* Out = OutB + (size_t)z * (M_TOT * D_MODEL);
  int m0 = blockIdx.y * 128, n0 = blockIdx.x * 128;
  f32x4 acc[4][4] = {};
  gemm_core_128(A, Bt, sA, sB, acc, m0, n0);

  int tid = threadIdx.x, lane = tid & 63, wave = tid >> 6;
  int l15 = lane & 15, quad = lane >> 4;
  int wm = (wave >> 1) * 64, wn = (wave & 1) * 64;
  float bvv[4];
#pragma unroll
  for (int ni = 0; ni < 4; ni++) bvv[ni] = bias[n0 + wn + ni * 16 + l15];

  if (z < 2) { // Q/K: RoPE fused; Q also prescaled 0.125*log2e
    float qs = (z == 0) ? 0.125f * LOG2E : 1.0f;
#pragma unroll
    for (int mi = 0; mi < 4; mi++) {
#pragma unroll
      for (int r = 0; r < 4; r++) {
        int m = m0 + wm + mi * 16 + quad * 4 + r; // global row = b*T + t
        size_t ro = (size_t)m * D_MODEL + n0 + wn;
        int tl = m & (T_SEQ - 1);
#pragma unroll
        for (int ni = 0; ni < 2; ni++) {
          int d = ni * 16 + l15; // < 32; pair (d, d+32) in regs ni, ni+2
          float c = ctab[tl * 32 + d], s = stab[tl * 32 + d];
          float xl = acc[mi][ni][r] + bvv[ni];
          float xr = acc[mi][ni + 2][r] + bvv[ni + 2];
          ((__bf16*)Out)[ro + d] = (__bf16)((xl * c - xr * s) * qs);
          ((__bf16*)Out)[ro + d + 32] = (__bf16)((xl * s + xr * c) * qs);
        }
      }
    }
  } else { // V: write transposed Vb[b][h][d][t] (wave's 64 cols = one head)
    int hh = (n0 + wn) >> 6;
    int mbase = m0 + wm;
    int bb = mbase >> 11; // tile never crosses batch (2048 % 128 == 0)
    int tbase = mbase & (T_SEQ - 1);
    u16* Vw = Vb + (size_t)(bb * NHEAD + hh) * HDIM * T_SEQ;
#pragma unroll
    for (int mi = 0; mi < 4; mi++)
#pragma unroll
      for (int r = 0; r < 4; r++) {
        int t = tbase + mi * 16 + quad * 4 + r;
#pragma unroll
        for (int ni = 0; ni < 4; ni++) {
          int d = ni * 16 + l15;
          ((__bf16*)Vw)[(size_t)d * T_SEQ + t] = (__bf16)(acc[mi][ni][r] + bvv[ni]);
        }
      }
  }
}

// Output projection: ctx bf16 @ Wo^T + bo -> f32 d_out. 64x64 tiles, grid
// (16, 64) = 1024 blocks = 4 blocks/CU (LDS 16 KB): four independent blocks
// per CU stagger barrier drains. Wave-tile 32x32, BK=64 plane staging.
__global__ __launch_bounds__(256) void k_gemm_out(
    const u16* __restrict__ ctx, const u16* __restrict__ Wot,
    const float* __restrict__ bo, float* __restrict__ Cout) {
  __shared__ __align__(16) u16 sA[64 * 64];
  __shared__ __align__(16) u16 sB[64 * 64];
  const int K = D_MODEL;
  int m0 = blockIdx.y * 64, n0 = blockIdx.x * 64;
  int tid = threadIdx.x, lane = tid & 63, wave = tid >> 6;
  int l15 = lane & 15, quad = lane >> 4;
  int wm = (wave >> 1) * 32, wn = (wave & 1) * 32;
  int r0 = tid >> 2, pcol0 = (tid & 3) * 8;
  const u16* A0 = ctx + (size_t)(m0 + r0) * K + pcol0;
  const u16* B0 = Wot + (size_t)(n0 + r0) * K + pcol0;
  u16* dA = sA + wave * 512; // one call = one full 64x32 plane (256 thr)
  u16* dB = sB + wave * 512;
  f32x4 acc[2][2] = {};
  for (int k0 = 0; k0 < K; k0 += 64) {
    __syncthreads(); // previous iter's frag reads done
    gl2lds16(A0 + k0, dA);
    gl2lds16(A0 + k0 + 32, dA + 2048); // plane1
    gl2lds16(B0 + k0, dB);
    gl2lds16(B0 + k0 + 32, dB + 2048);
    __syncthreads(); // barrier drain -> LDS data visible
#pragma unroll
    for (int kh = 0; kh < 2; kh++) {
      bf8v af[2], bf[2];
#pragma unroll
      for (int i = 0; i < 2; i++)
        af[i] = *(const bf8v*)(sA + kh * 2048 + (wm + i * 16 + l15) * 32 + quad * 8);
#pragma unroll
      for (int i = 0; i < 2; i++)
        bf[i] = *(const bf8v*)(sB + kh * 2048 + (wn + i * 16 + l15) * 32 + quad * 8);
#pragma unroll
      for (int mi = 0; mi < 2; mi++)
#pragma unroll
        for (int ni = 0; ni < 2; ni++)
          acc[mi][ni] = __builtin_amdgcn_mfma_f32_16x16x32_bf16(
              af[mi], bf[ni], acc[mi][ni], 0, 0, 0);
    }
  }
  float bvv[2];
#pragma unroll
  for (int ni = 0; ni < 2; ni++) bvv[ni] = bo[n0 + wn + ni * 16 + l15];
#pragma unroll
  for (int mi = 0; mi < 2; mi++)
#pragma unroll
    for (int r = 0; r < 4; r++) {
      size_t ro = (size_t)(m0 + wm + mi * 16 + quad * 4 + r) * D_MODEL + n0 + wn;
#pragma unroll
      for (int ni = 0; ni < 2; ni++)
        Cout[ro + ni * 16 + l15] = acc[mi][ni][r] + bvv[ni];
    }
}

// ---------------------------------------------------------------------------
// Flash attention v10: grid (T/128, B*H) XCD-swizzled, 512 thr = 8 waves.
// Wave w: q sub-tile qw = w&3 (32 rows), key half kh = w>>2. exp2-native
// softmax without max-subtraction => key halves accumulate independent
// unnormalized (O, l), merged once at the end via LDS.
// K/V double-buffered global_load_lds DMA, ONE __syncthreads per tile
// (R8 structure). P transpose is IN-REGISTER (cvt_pk + permlane swaps):
// no P LDS, no lgkmcnt stalls, no P bank conflicts.
__global__ __launch_bounds__(512, 4) void k_attn(
    const u16* __restrict__ Qr, const u16* __restrict__ Kr,
    const u16* __restrict__ Vb, const float* __restrict__ frac,
    const float* __restrict__ alpha_pos, const float* __restrict__ alpha_neg,
    u16* __restrict__ ctx) {
  // smem carve (u16 elems):
  //   [0,8192)       kT[2][4096]  swizzled [key][d]
  //   [8192,16384)   vT[2][4096]  swizzled [d][key]
  //   [16384,20480)  fLds: f32[2048] frac row for this batch
  // merge phase reuses [0,16896) as f32 O-scratch, [16896,17152) l-scratch.
  __shared__ __align__(16) u16 smem[20480];
  // ---- XCD swizzle: lin%8 = XCD (round-robin). Give each XCD 4 whole heads
  // so all 16 q-blocks of a head share one L2 (K/V single-fetch per XCD).
  int lin = blockIdx.x + (blockIdx.y << 4);
  int xcd = lin & 7, slot = lin >> 3;
  int bh = (xcd << 2) | (slot >> 4);
  int q0 = (slot & 15) << 7;
  int b = bh >> 4, h = bh & 15;
  int tid = threadIdx.x, wave = tid >> 6, lane = tid & 63;
  int l15 = lane & 15, quad = lane >> 4;
  int qw = wave & 3;  // q sub-tile (32 rows)
  int kh = wave >> 2; // key half within each 64-key tile

  const u16* Kh = Kr + (size_t)b * T_SEQ * D_MODEL + h * HDIM;
  const u16* Vh = Vb + (size_t)bh * HDIM * T_SEQ;
  const float* fb = frac + b * T_SEQ;

  u16* kT0 = smem;
  u16* vT0 = smem + 8192;
  float* fl = (float*)(smem + 16384);

  // Q B-frags (B[k=d][n=q] = Q[q][d]): lane holds Q[q=l15][d=quad*8+j]
  bf8v qf[2][2];
  float fq[2];
#pragma unroll
  for (int g = 0; g < 2; g++) {
    int qrow = q0 + qw * 32 + g * 16 + l15;
    const u16* qbase =
        Qr + (size_t)(b * T_SEQ + qrow) * D_MODEL + h * HDIM + quad * 8;
    qf[g][0] = *(const bf8v*)qbase;
    qf[g][1] = *(const bf8v*)(qbase + 32);
    fq[g] = fb[qrow]; // S^T col = q = l15
  }
  // frac -> LDS (512 thr x 4 floats = 2048)
  {
    f32x4 fv = *(const f32x4*)(fb + (tid << 2));
    *(f32x4*)(fl + (tid << 2)) = fv;
  }

  // bias = ap*max(dd,0)+an*min(dd,0) = c1*dd + c2*|dd| (log2 domain)
  float ap = alpha_pos[h] * LOG2E, an = alpha_neg[h] * LOG2E;
  float c1 = 0.5f * (ap + an), c2 = 0.5f * (ap - an);
  bf8v onesv;
#pragma unroll
  for (int j = 0; j < 8; j++) onesv[j] = (__bf16)1.0f;
  f32x4 zero4 = {};
  f32x4 o[2][4] = {};
  f32x4 o_l[2] = {};

  // Hoisted frag offsets (elems). Swizzle: row r, chunk gc -> pc = gc^(r&7).
  int x0 = (quad ^ (l15 & 7)) * 8;
  int kidx[2], vidx[4];
#pragma unroll
  for (int nt = 0; nt < 2; nt++) // K rows kh*32 + nt*16 + l15
    kidx[nt] = (((kh * 2 + nt) * 16 + l15) << 6) + x0;
#pragma unroll
  for (int dt = 0; dt < 4; dt++) // V keys chunk quad + kh*4
    vidx[dt] = (((dt * 16 + l15) << 6) + x0) ^ (kh * 32);

  // DMA staging map: 512 threads x 1 chunk per array per tile.
  // chunk p = tid; row = p>>3, pc = p&7; fetch global chunk gc = pc^(row&7).
  int kr0 = tid >> 3, gc0 = (tid & 7) ^ (kr0 & 7);
  const u16* kg0 = Kh + (size_t)kr0 * D_MODEL + gc0 * 8;
  const u16* vg0 = Vh + (size_t)kr0 * T_SEQ + gc0 * 8; // row = d here
  int woff = wave * 512; // wave-uniform LDS dest (elems); lane -> +lane*8

  auto stage = [&](int bufoff, int kbase) {
    gl2lds16(kg0 + (size_t)kbase * D_MODEL, kT0 + bufoff + woff);
    gl2lds16(vg0 + kbase, vT0 + bufoff + woff);
  };

  stage(0, 0);
  __syncthreads(); // DMA + frac-LDS visible

#pragma unroll 2
  for (int kt = 0; kt < T_SEQ / 64; kt++) {
    int kbase = kt * 64;
    int bo = (kt & 1) * 4096;
    if (kt + 1 < T_SEQ / 64) stage(bo ^ 4096, kbase + 64);
    const u16* kb = kT0 + bo;
    const u16* vb = vT0 + bo;

    // K A-frags for this wave's key half: rows kh*32 + nt*16 + l15
    bf8v kf0[2], kf1[2];
#pragma unroll
    for (int nt = 0; nt < 2; nt++) {
      kf0[nt] = *(const bf8v*)(kb + kidx[nt]);
      kf1[nt] = *(const bf8v*)(kb + (kidx[nt] ^ 32));
    }
    // V B-frags: rows d = dt*16+l15; key chunks kh*4 + quad
    bf8v vf[4];
#pragma unroll
    for (int dt = 0; dt < 4; dt++) vf[dt] = *(const bf8v*)(vb + vidx[dt]);
    // frac[key] for this lane's 4 keys per nt (LDS, 16-lane broadcast)
    f32x4 fk4[2];
#pragma unroll
    for (int nt = 0; nt < 2; nt++)
      fk4[nt] = *(const f32x4*)(fl + kbase + kh * 32 + nt * 16 + quad * 4);

#pragma unroll
    for (int g = 0; g < 2; g++) {
      float fqg = fq[g];
      // wrd = [A0, A1, B0, B1]: A_m from nt0 keys {4q+2m,+1}, B_m from nt1.
      unsigned int wrd[4];
#pragma unroll
      for (int nt = 0; nt < 2; nt++) {
        // S^T tile: D[row=key_loc=nt*16+quad*4+r][col=q=l15], log2 domain
        f32x4 s = zero4;
        s = __builtin_amdgcn_mfma_f32_16x16x32_bf16(kf0[nt], qf[g][0], s, 0, 0, 0);
        s = __builtin_amdgcn_mfma_f32_16x16x32_bf16(kf1[nt], qf[g][1], s, 0, 0, 0);
        float p[4];
#pragma unroll
        for (int r = 0; r < 4; r++) {
          float dd = fk4[nt][r] - fqg;
          p[r] = __builtin_amdgcn_exp2f(
              fmaf(c2, __builtin_fabsf(dd), fmaf(c1, dd, s[r])));
        }
        unsigned int w0, w1;
        asm("v_cvt_pk_bf16_f32 %0, %1, %2" : "=v"(w0) : "v"(p[0]), "v"(p[1]));
        asm("v_cvt_pk_bf16_f32 %0, %1, %2" : "=v"(w1) : "v"(p[2]), "v"(p[3]));
        wrd[nt * 2 + 0] = w0;
        wrd[nt * 2 + 1] = w1;
      }
      // In-register P transpose. permlane32_swap: X'={Xq0,Xq1,Yq0,Yq1},
      // Y'={Xq2,Xq3,Yq2,Yq3}. permlane16_swap: X''={X'r0,Y'r0,X'r2,Y'r2},
      // Y''={X'r1,Y'r1,X'r3,Y'r3}. (A0,B0)->(W0,W2); (A1,B1)->(W1,W3):
      // lane quad q ends with keys {8q..8q+7} = PV A-frag for m=l15.
      asm("v_permlane32_swap_b32 %0, %1" : "+v"(wrd[0]), "+v"(wrd[2]));
      asm("v_permlane16_swap_b32 %0, %1" : "+v"(wrd[0]), "+v"(wrd[2]));
      asm("v_permlane32_swap_b32 %0, %1" : "+v"(wrd[1]), "+v"(wrd[3]));
      asm("v_permlane16_swap_b32 %0, %1" : "+v"(wrd[1]), "+v"(wrd[3]));
      u32x4v pw_;
      pw_.x = wrd[0]; pw_.y = wrd[1]; pw_.z = wrd[2]; pw_.w = wrd[3];
      bf8v pf = __builtin_bit_cast(bf8v, pw_);
      // O_g += P_g @ V_half ; l_g += P_g @ ones.
      o_l[g] = __builtin_amdgcn_mfma_f32_16x16x32_bf16(pf, onesv, o_l[g], 0, 0, 0);
#pragma unroll
      for (int dt = 0; dt < 4; dt++)
        o[g][dt] = __builtin_amdgcn_mfma_f32_16x16x32_bf16(pf, vf[dt],
                                                           o[g][dt], 0, 0, 0);
    }
    __syncthreads(); // drains this iter's DMA (vmcnt) + frees cur buf
  }

  // ---- merge key halves. kh==1 waves publish (O,l); kh==0 combine+store.
  float* Of = (float*)smem;             // [128 q][66] f32 = 33792 B
  float* Lf = (float*)(smem + 16896);   // 128 f32
  if (kh == 1) {
#pragma unroll
    for (int g = 0; g < 2; g++)
#pragma unroll
      for (int r = 0; r < 4; r++) {
        int ql = qw * 32 + g * 16 + quad * 4 + r;
#pragma unroll
        for (int dt = 0; dt < 4; dt++)
          Of[ql * 66 + dt * 16 + l15] = o[g][dt][r];
        if (l15 == 0) Lf[ql] = o_l[g][r];
      }
  }
  __syncthreads();
  if (kh == 0) {
#pragma unroll
    for (int g = 0; g < 2; g++)
#pragma unroll
      for (int r = 0; r < 4; r++) {
        int ql = qw * 32 + g * 16 + quad * 4 + r;
        float linv = 1.0f / (o_l[g][r] + Lf[ql]);
        __bf16* orow =
            (__bf16*)(ctx + (size_t)(b * T_SEQ + q0 + ql) * D_MODEL + h * HDIM);
#pragma unroll
        for (int dt = 0; dt < 4; dt++)
          orow[dt * 16 + l15] =
              (__bf16)((o[g][dt][r] + Of[ql * 66 + dt * 16 + l15]) * linv);
      }
  }
}

// ---------------------------------------------------------------------------
extern "C" void kernel_launch(void* const* d_in, const int* in_sizes, int n_in,
                              void* d_out, int out_size, void* d_ws,
                              size_t ws_size, hipStream_t stream) {
  const float* q = (const float*)d_in[0];
  const float* k = (const float*)d_in[1];
  const float* v = (const float*)d_in[2];
  const float* frac = (const float*)d_in[3];
  const float* Wq = (const float*)d_in[4];
  const float* Wk = (const float*)d_in[5];
  const float* Wv = (const float*)d_in[6];
  const float* Wo = (const float*)d_in[7];
  const float* bq = (const float*)d_in[8];
  const float* bk = (const float*)d_in[9];
  const float* bv = (const float*)d_in[10];
  const float* bo = (const float*)d_in[11];
  const float* alpha_pos = (const float*)d_in[12];
  const float* alpha_neg = (const float*)d_in[13];

  char* ws = (char*)d_ws;
  u16* Xb = (u16*)(ws + 0);
  u16* Wt = (u16*)(ws + 25165824);
  u16* Qr = (u16*)(ws + 33554432);
  u16* Kr = (u16*)(ws + 41943040);
  u16* Vtmp = (u16*)(ws + 50331648); // holds ctx
  u16* Vb = (u16*)(ws + 58720256);
  float* ctab = (float*)(ws + 67108864);
  float* stab = (float*)(ws + 67371008);
  u16* ctx = Vtmp;
  u16* QKVout = Qr; // Qr,Kr contiguous; z==2 writes Vb directly

  k_prep<<<dim3(7424), 256, 0, stream>>>(q, k, v, Wq, Wk, Wv, Wo, Xb, Wt, ctab,
                                         stab);
  k_gemm_qkv<<<dim3(8, 32, 3), 256, 0, stream>>>(Xb, Wt, bq, bk, bv, ctab, stab,
                                                 QKVout, Vb);
  k_attn<<<dim3(16, 32), 512, 0, stream>>>(Qr, Kr, Vb, frac, alpha_pos,
                                           alpha_neg, ctx);
  k_gemm_out<<<dim3(16, 64), 256, 0, stream>>>(ctx, Wt + 3 * 1048576, bo,
                                               (float*)d_out);
}

// Round 4
// 230.574 us; speedup vs baseline: 1.1108x; 1.0046x over previous
//
#include <hip/hip_runtime.h>

// ---------------------------------------------------------------------------
// CustomMultiHeadAttentionStoich: fused MHA with RoPE + frac-difference bias.
// B=2 T=2048 D_MODEL=1024 H=16 hd=64. All matmuls via mfma_f32_16x16x32_bf16.
//
// Verified gfx950 fragment layouts (learn_hip m89/m91, rounds 1-6 pass):
//   A-frag : lane holds A[m=lane&15][k=(lane>>4)*8 + j], j=0..7  (8 bf16, 16B)
//   B-frag : lane holds B[k=(lane>>4)*8 + j][n=lane&15]
//   C/D    : lane holds D[row=(lane>>4)*4 + r][col=lane&15], r=0..3 (4 f32)
//
// Round-11 changes (projection GEMMs; R10 post-mortem: k_attn fixed, crown
// moved to k_gemm_qkv at 65 us with MfmaUtil 15/VALU 13/HBM 25% = pure
// latency-bound: 2-barrier loop drains vmcnt(0) every K-step, and the
// default XCD mapping puts the 8 n-blocks of one A-panel on 8 XCDs):
//  * gemm_core_128 + k_gemm_out loop -> double-buffered LDS with counted
//    s_waitcnt vmcnt(N) + raw s_barrier (no vmcnt(0) in loop): stage(t+1)
//    issued first, wait vmcnt(8|4) = own stage(t) landed, barrier, compute.
//    DMA latency for t+1 hides under compute(t).
//  * XCD swizzle both GEMMs: each XCD owns consecutive m-panels x ALL
//    n-blocks -> A-panel + full weight fit its 4MB L2 (A 1MB + B 2MB).
//  * k_attn / k_prep untouched (attribution).
// ---------------------------------------------------------------------------

typedef unsigned short u16;
typedef __bf16 bf8v __attribute__((ext_vector_type(8)));
typedef __bf16 bf4v __attribute__((ext_vector_type(4)));
typedef float f32x4 __attribute__((ext_vector_type(4)));
typedef unsigned int u32x4v __attribute__((ext_vector_type(4)));

#define D_MODEL 1024
#define T_SEQ   2048
#define NHEAD   16
#define HDIM    64
#define BATCH   2
#define M_TOT   (BATCH * T_SEQ) /* 4096 */
#define LOG2E   1.4426950408889634f

__device__ __forceinline__ void gl2lds16(const u16* g, u16* l) {
  __builtin_amdgcn_global_load_lds(
      (__attribute__((address_space(1))) void*)g,
      (__attribute__((address_space(3))) void*)l, 16, 0, 0);
}

// ---------------------------------------------------------------------------
// k_prep: zone-partitioned prep work in ONE launch.
//   blocks [0,6144)    : f32->bf16 convert of q/k/v into Xb
//   blocks [6144,7168) : W^T bf16 transpose of Wq/Wk/Wv/Wo into WtB
//   blocks [7168,7424) : RoPE cos/sin table
__global__ __launch_bounds__(256) void k_prep(
    const float* __restrict__ q, const float* __restrict__ k,
    const float* __restrict__ v, const float* __restrict__ Wq,
    const float* __restrict__ Wk, const float* __restrict__ Wv,
    const float* __restrict__ Wo, u16* __restrict__ Xb, u16* __restrict__ WtB,
    float* __restrict__ ct, float* __restrict__ st) {
  __shared__ float tile[64 * 65];
  int bx = blockIdx.x, tid = threadIdx.x;
  if (bx < 6144) { // ---- convert zone
    int z = bx >> 11, xb = bx & 2047;
    const float* src = (z == 0) ? q : (z == 1) ? k : v;
    u16* dst = Xb + (size_t)z * (M_TOT * D_MODEL);
    int idx = (xb * 256 + tid) * 8;
    float4 a = *(const float4*)(src + idx);
    float4 b = *(const float4*)(src + idx + 4);
    bf8v o;
    o[0] = (__bf16)a.x; o[1] = (__bf16)a.y; o[2] = (__bf16)a.z; o[3] = (__bf16)a.w;
    o[4] = (__bf16)b.x; o[5] = (__bf16)b.y; o[6] = (__bf16)b.z; o[7] = (__bf16)b.w;
    *(bf8v*)(dst + idx) = o;
  } else if (bx < 7168) { // ---- W transpose zone (64x64 tiles, stride 65)
    int idx2 = bx - 6144;
    int z = idx2 >> 8, rem = idx2 & 255;
    int k0 = (rem >> 4) * 64, n0 = (rem & 15) * 64;
    const float* W = (z == 0) ? Wq : (z == 1) ? Wk : (z == 2) ? Wv : Wo;
    u16* Wt = WtB + (size_t)z * (D_MODEL * D_MODEL);
#pragma unroll
    for (int i = 0; i < 16; i++) {
      int idx = tid + i * 256;
      int r = idx >> 6, c = idx & 63;
      tile[c * 65 + r] = W[(size_t)(k0 + r) * D_MODEL + n0 + c];
    }
    __syncthreads();
#pragma unroll
    for (int i = 0; i < 16; i++) {
      int idx = tid + i * 256;
      int r = idx >> 6, c = idx & 63;
      ((__bf16*)Wt)[(size_t)(n0 + r) * D_MODEL + k0 + c] = (__bf16)tile[r * 65 + c];
    }
  } else { // ---- RoPE table zone: angle(t,d) = t / 10000^(d/32)
    int idx = (bx - 7168) * 256 + tid; // = t*32 + d
    int t = idx >> 5, d = idx & 31;
    float ang = (float)t * powf(10000.0f, -(float)d * (1.0f / 32.0f));
    ct[idx] = cosf(ang);
    st[idx] = sinf(ang);
  }
}

// ---------------------------------------------------------------------------
// QKV GEMM core v2: C = A[M][K] @ Bt[N][K]^T, K=1024, BK=64, BM=BN=128.
// DOUBLE-buffered global_load_lds staging with counted vmcnt:
//   per iter: B1(s_barrier: all reads of buf[t-1] done) -> stage(t+1) ->
//   vmcnt(8) (own stage(t) landed; stage(t+1) flying) -> B2(s_barrier:
//   ALL waves' stage(t) landed) -> ds_read+MFMA on buf[t].
// No vmcnt(0) drain in the main loop.
__device__ __forceinline__ void gemm_core_128(const u16* __restrict__ A,
                                              const u16* __restrict__ Bt,
                                              u16* sA, u16* sB,
                                              f32x4 (&acc)[4][4],
                                              int m0, int n0) {
  const int K = D_MODEL;
  const int NT = K / 64; // 16
  int tid = threadIdx.x;
  int lane = tid & 63, wave = tid >> 6;
  int l15 = lane & 15, quad = lane >> 4;
  int wm = (wave >> 1) * 64, wn = (wave & 1) * 64;
  int r0 = tid >> 2, pcol0 = (tid & 3) * 8;
  int r1 = 64 + r0;
  const u16* A0 = A + (size_t)(m0 + r0) * K + pcol0;
  const u16* A1 = A + (size_t)(m0 + r1) * K + pcol0;
  const u16* B0 = Bt + (size_t)(n0 + r0) * K + pcol0;
  const u16* B1 = Bt + (size_t)(n0 + r1) * K + pcol0;
  u16* dA0 = sA + wave * 512;        // plane0, rows 0..63 (wave-uniform base)
  u16* dA1 = sA + 2048 + wave * 512; // plane0, rows 64..127
  u16* dB0 = sB + wave * 512;
  u16* dB1 = sB + 2048 + wave * 512;
  auto stg = [&](int bo, int k0) {
    gl2lds16(A0 + k0, dA0 + bo);
    gl2lds16(A1 + k0, dA1 + bo);
    gl2lds16(A0 + k0 + 32, dA0 + 4096 + bo); // plane1
    gl2lds16(A1 + k0 + 32, dA1 + 4096 + bo);
    gl2lds16(B0 + k0, dB0 + bo);
    gl2lds16(B0 + k0 + 32, dB0 + 4096 + bo);
    gl2lds16(B1 + k0, dB1 + bo);
    gl2lds16(B1 + k0 + 32, dB1 + 4096 + bo);
  };
  stg(0, 0);
  for (int t = 0; t < NT; t++) {
    int bo = (t & 1) * 8192;
    __builtin_amdgcn_s_barrier(); // B1: all waves done reading buf[t-1]
    if (t + 1 < NT) {
      stg(bo ^ 8192, (t + 1) * 64);
      asm volatile("s_waitcnt vmcnt(8)" ::: "memory"); // stage(t) landed
    } else {
      asm volatile("s_waitcnt vmcnt(0)" ::: "memory"); // last: drain
    }
    __builtin_amdgcn_s_barrier(); // B2: all waves' stage(t) landed
#pragma unroll
    for (int kh = 0; kh < 2; kh++) {
      bf8v af[4], bf[4];
#pragma unroll
      for (int i = 0; i < 4; i++)
        af[i] = *(const bf8v*)(sA + bo + kh * 4096 + (wm + i * 16 + l15) * 32 + quad * 8);
#pragma unroll
      for (int i = 0; i < 4; i++)
        bf[i] = *(const bf8v*)(sB + bo + kh * 4096 + (wn + i * 16 + l15) * 32 + quad * 8);
#pragma unroll
      for (int mi = 0; mi < 4; mi++)
#pragma unroll
        for (int ni = 0; ni < 4; ni++)
          acc[mi][ni] = __builtin_amdgcn_mfma_f32_16x16x32_bf16(
              af[mi], bf[ni], acc[mi][ni], 0, 0, 0);
    }
  }
}

// QKV projection, grid (8, 32, 3). XCD-swizzled: XCD = bx (lin%8); each XCD
// owns 4 consecutive m-panels x all 8 n-blocks -> A 1MB + B 2MB L2-resident.
// z<2 -> RoPE fused; z==0 prescales Q by 0.125*log2e. z==2 writes projected
// V DIRECTLY TRANSPOSED into Vb[b][h][d][t].
__global__ __launch_bounds__(256) void k_gemm_qkv(
    const u16* __restrict__ Xb, const u16* __restrict__ WtB,
    const float* __restrict__ bq, const float* __restrict__ bk,
    const float* __restrict__ bv, const float* __restrict__ ctab,
    const float* __restrict__ stab, u16* __restrict__ OutB,
    u16* __restrict__ Vb) {
  __shared__ __align__(16) u16 sA[2 * 128 * 64];
  __shared__ __align__(16) u16 sB[2 * 128 * 64];
  int z = blockIdx.z;
  const u16* A = Xb + (size_t)z * (M_TOT * D_MODEL);
  const u16* Bt = WtB + (size_t)z * (D_MODEL * D_MODEL);
  const float* bias = (z == 0) ? bq : (z == 1) ? bk : bv;
  u16* Out = OutB + (size_t)z * (M_TOT * D_MODEL);
  // XCD swizzle: xcd = blockIdx.x (grid x=8; lin%8 = bx since 8|8*by, 8|256*bz)
  int mblk = (blockIdx.x << 2) | (blockIdx.y >> 3);
  int nblk = blockIdx.y & 7;
  int m0 = mblk * 128, n0 = nblk * 128;
  f32x4 acc[4][4] = {};
  gemm_core_128(A, Bt, sA, sB, acc, m0, n0);

  int tid = threadIdx.x, lane = tid & 63, wave = tid >> 6;
  int l15 = lane & 15, quad = lane >> 4;
  int wm = (wave >> 1) * 64, wn = (wave & 1) * 64;
  float bvv[4];
#pragma unroll
  for (int ni = 0; ni < 4; ni++) bvv[ni] = bias[n0 + wn + ni * 16 + l15];

  if (z < 2) { // Q/K: RoPE fused; Q also prescaled 0.125*log2e
    float qs = (z == 0) ? 0.125f * LOG2E : 1.0f;
#pragma unroll
    for (int mi = 0; mi < 4; mi++) {
#pragma unroll
      for (int r = 0; r < 4; r++) {
        int m = m0 + wm + mi * 16 + quad * 4 + r; // global row = b*T + t
        size_t ro = (size_t)m * D_MODEL + n0 + wn;
        int tl = m & (T_SEQ - 1);
#pragma unroll
        for (int ni = 0; ni < 2; ni++) {
          int d = ni * 16 + l15; // < 32; pair (d, d+32) in regs ni, ni+2
          float c = ctab[tl * 32 + d], s = stab[tl * 32 + d];
          float xl = acc[mi][ni][r] + bvv[ni];
          float xr = acc[mi][ni + 2][r] + bvv[ni + 2];
          ((__bf16*)Out)[ro + d] = (__bf16)((xl * c - xr * s) * qs);
          ((__bf16*)Out)[ro + d + 32] = (__bf16)((xl * s + xr * c) * qs);
        }
      }
    }
  } else { // V: write transposed Vb[b][h][d][t] (wave's 64 cols = one head)
    int hh = (n0 + wn) >> 6;
    int mbase = m0 + wm;
    int bb = mbase >> 11; // tile never crosses batch (2048 % 128 == 0)
    int tbase = mbase & (T_SEQ - 1);
    u16* Vw = Vb + (size_t)(bb * NHEAD + hh) * HDIM * T_SEQ;
#pragma unroll
    for (int mi = 0; mi < 4; mi++)
#pragma unroll
      for (int r = 0; r < 4; r++) {
        int t = tbase + mi * 16 + quad * 4 + r;
#pragma unroll
        for (int ni = 0; ni < 4; ni++) {
          int d = ni * 16 + l15;
          ((__bf16*)Vw)[(size_t)d * T_SEQ + t] = (__bf16)(acc[mi][ni][r] + bvv[ni]);
        }
      }
  }
}

// Output projection: ctx bf16 @ Wo^T + bo -> f32 d_out. 64x64 tiles, grid
// (16, 64) = 1024 blocks, XCD-swizzled (8 m-panels x 16 n per XCD: A 1MB +
// B 2MB L2-resident). Double-buffered staging with counted vmcnt(4).
__global__ __launch_bounds__(256) void k_gemm_out(
    const u16* __restrict__ ctx, const u16* __restrict__ Wot,
    const float* __restrict__ bo, float* __restrict__ Cout) {
  __shared__ __align__(16) u16 sA[2 * 64 * 64];
  __shared__ __align__(16) u16 sB[2 * 64 * 64];
  const int K = D_MODEL;
  const int NT = K / 64; // 16
  // XCD swizzle: lin = bx + 16*by -> xcd = bx&7. Per-xcd slot: (bx>>3)*64+by.
  int xcd = blockIdx.x & 7;
  int idx = ((blockIdx.x >> 3) << 6) | blockIdx.y; // 0..127
  int m0 = (xcd * 8 + (idx >> 4)) * 64;
  int n0 = (idx & 15) * 64;
  int tid = threadIdx.x, lane = tid & 63, wave = tid >> 6;
  int l15 = lane & 15, quad = lane >> 4;
  int wm = (wave >> 1) * 32, wn = (wave & 1) * 32;
  int r0 = tid >> 2, pcol0 = (tid & 3) * 8;
  const u16* A0 = ctx + (size_t)(m0 + r0) * K + pcol0;
  const u16* B0 = Wot + (size_t)(n0 + r0) * K + pcol0;
  u16* dA = sA + wave * 512; // one call = one full 64x32 plane (256 thr)
  u16* dB = sB + wave * 512;
  auto stg = [&](int bo, int k0) {
    gl2lds16(A0 + k0, dA + bo);
    gl2lds16(A0 + k0 + 32, dA + 2048 + bo); // plane1
    gl2lds16(B0 + k0, dB + bo);
    gl2lds16(B0 + k0 + 32, dB + 2048 + bo);
  };
  f32x4 acc[2][2] = {};
  stg(0, 0);
  for (int t = 0; t < NT; t++) {
    int bo = (t & 1) * 4096;
    __builtin_amdgcn_s_barrier(); // B1: all waves done reading buf[t-1]
    if (t + 1 < NT) {
      stg(bo ^ 4096, (t + 1) * 64);
      asm volatile("s_waitcnt vmcnt(4)" ::: "memory"); // stage(t) landed
    } else {
      asm volatile("s_waitcnt vmcnt(0)" ::: "memory");
    }
    __builtin_amdgcn_s_barrier(); // B2: all waves' stage(t) landed
#pragma unroll
    for (int kh = 0; kh < 2; kh++) {
      bf8v af[2], bf[2];
#pragma unroll
      for (int i = 0; i < 2; i++)
        af[i] = *(const bf8v*)(sA + bo + kh * 2048 + (wm + i * 16 + l15) * 32 + quad * 8);
#pragma unroll
      for (int i = 0; i < 2; i++)
        bf[i] = *(const bf8v*)(sB + bo + kh * 2048 + (wn + i * 16 + l15) * 32 + quad * 8);
#pragma unroll
      for (int mi = 0; mi < 2; mi++)
#pragma unroll
        for (int ni = 0; ni < 2; ni++)
          acc[mi][ni] = __builtin_amdgcn_mfma_f32_16x16x32_bf16(
              af[mi], bf[ni], acc[mi][ni], 0, 0, 0);
    }
  }
  float bvv[2];
#pragma unroll
  for (int ni = 0; ni < 2; ni++) bvv[ni] = bo[n0 + wn + ni * 16 + l15];
#pragma unroll
  for (int mi = 0; mi < 2; mi++)
#pragma unroll
    for (int r = 0; r < 4; r++) {
      size_t ro = (size_t)(m0 + wm + mi * 16 + quad * 4 + r) * D_MODEL + n0 + wn;
#pragma unroll
      for (int ni = 0; ni < 2; ni++)
        Cout[ro + ni * 16 + l15] = acc[mi][ni][r] + bvv[ni];
    }
}

// ---------------------------------------------------------------------------
// Flash attention v10: grid (T/128, B*H) XCD-swizzled, 512 thr = 8 waves.
// Wave w: q sub-tile qw = w&3 (32 rows), key half kh = w>>2. exp2-native
// softmax without max-subtraction => key halves accumulate independent
// unnormalized (O, l), merged once at the end via LDS.
// K/V double-buffered global_load_lds DMA, ONE __syncthreads per tile
// (R8 structure). P transpose is IN-REGISTER (cvt_pk + permlane swaps):
// no P LDS, no lgkmcnt stalls, no P bank conflicts.
__global__ __launch_bounds__(512, 4) void k_attn(
    const u16* __restrict__ Qr, const u16* __restrict__ Kr,
    const u16* __restrict__ Vb, const float* __restrict__ frac,
    const float* __restrict__ alpha_pos, const float* __restrict__ alpha_neg,
    u16* __restrict__ ctx) {
  // smem carve (u16 elems):
  //   [0,8192)       kT[2][4096]  swizzled [key][d]
  //   [8192,16384)   vT[2][4096]  swizzled [d][key]
  //   [16384,20480)  fLds: f32[2048] frac row for this batch
  // merge phase reuses [0,16896) as f32 O-scratch, [16896,17152) l-scratch.
  __shared__ __align__(16) u16 smem[20480];
  // ---- XCD swizzle: lin%8 = XCD (round-robin). Give each XCD 4 whole heads
  // so all 16 q-blocks of a head share one L2 (K/V single-fetch per XCD).
  int lin = blockIdx.x + (blockIdx.y << 4);
  int xcd = lin & 7, slot = lin >> 3;
  int bh = (xcd << 2) | (slot >> 4);
  int q0 = (slot & 15) << 7;
  int b = bh >> 4, h = bh & 15;
  int tid = threadIdx.x, wave = tid >> 6, lane = tid & 63;
  int l15 = lane & 15, quad = lane >> 4;
  int qw = wave & 3;  // q sub-tile (32 rows)
  int kh = wave >> 2; // key half within each 64-key tile

  const u16* Kh = Kr + (size_t)b * T_SEQ * D_MODEL + h * HDIM;
  const u16* Vh = Vb + (size_t)bh * HDIM * T_SEQ;
  const float* fb = frac + b * T_SEQ;

  u16* kT0 = smem;
  u16* vT0 = smem + 8192;
  float* fl = (float*)(smem + 16384);

  // Q B-frags (B[k=d][n=q] = Q[q][d]): lane holds Q[q=l15][d=quad*8+j]
  bf8v qf[2][2];
  float fq[2];
#pragma unroll
  for (int g = 0; g < 2; g++) {
    int qrow = q0 + qw * 32 + g * 16 + l15;
    const u16* qbase =
        Qr + (size_t)(b * T_SEQ + qrow) * D_MODEL + h * HDIM + quad * 8;
    qf[g][0] = *(const bf8v*)qbase;
    qf[g][1] = *(const bf8v*)(qbase + 32);
    fq[g] = fb[qrow]; // S^T col = q = l15
  }
  // frac -> LDS (512 thr x 4 floats = 2048)
  {
    f32x4 fv = *(const f32x4*)(fb + (tid << 2));
    *(f32x4*)(fl + (tid << 2)) = fv;
  }

  // bias = ap*max(dd,0)+an*min(dd,0) = c1*dd + c2*|dd| (log2 domain)
  float ap = alpha_pos[h] * LOG2E, an = alpha_neg[h] * LOG2E;
  float c1 = 0.5f * (ap + an), c2 = 0.5f * (ap - an);
  bf8v onesv;
#pragma unroll
  for (int j = 0; j < 8; j++) onesv[j] = (__bf16)1.0f;
  f32x4 zero4 = {};
  f32x4 o[2][4] = {};
  f32x4 o_l[2] = {};

  // Hoisted frag offsets (elems). Swizzle: row r, chunk gc -> pc = gc^(r&7).
  int x0 = (quad ^ (l15 & 7)) * 8;
  int kidx[2], vidx[4];
#pragma unroll
  for (int nt = 0; nt < 2; nt++) // K rows kh*32 + nt*16 + l15
    kidx[nt] = (((kh * 2 + nt) * 16 + l15) << 6) + x0;
#pragma unroll
  for (int dt = 0; dt < 4; dt++) // V keys chunk quad + kh*4
    vidx[dt] = (((dt * 16 + l15) << 6) + x0) ^ (kh * 32);

  // DMA staging map: 512 threads x 1 chunk per array per tile.
  // chunk p = tid; row = p>>3, pc = p&7; fetch global chunk gc = pc^(row&7).
  int kr0 = tid >> 3, gc0 = (tid & 7) ^ (kr0 & 7);
  const u16* kg0 = Kh + (size_t)kr0 * D_MODEL + gc0 * 8;
  const u16* vg0 = Vh + (size_t)kr0 * T_SEQ + gc0 * 8; // row = d here
  int woff = wave * 512; // wave-uniform LDS dest (elems); lane -> +lane*8

  auto stage = [&](int bufoff, int kbase) {
    gl2lds16(kg0 + (size_t)kbase * D_MODEL, kT0 + bufoff + woff);
    gl2lds16(vg0 + kbase, vT0 + bufoff + woff);
  };

  stage(0, 0);
  __syncthreads(); // DMA + frac-LDS visible

#pragma unroll 2
  for (int kt = 0; kt < T_SEQ / 64; kt++) {
    int kbase = kt * 64;
    int bo = (kt & 1) * 4096;
    if (kt + 1 < T_SEQ / 64) stage(bo ^ 4096, kbase + 64);
    const u16* kb = kT0 + bo;
    const u16* vb = vT0 + bo;

    // K A-frags for this wave's key half: rows kh*32 + nt*16 + l15
    bf8v kf0[2], kf1[2];
#pragma unroll
    for (int nt = 0; nt < 2; nt++) {
      kf0[nt] = *(const bf8v*)(kb + kidx[nt]);
      kf1[nt] = *(const bf8v*)(kb + (kidx[nt] ^ 32));
    }
    // V B-frags: rows d = dt*16+l15; key chunks kh*4 + quad
    bf8v vf[4];
#pragma unroll
    for (int dt = 0; dt < 4; dt++) vf[dt] = *(const bf8v*)(vb + vidx[dt]);
    // frac[key] for this lane's 4 keys per nt (LDS, 16-lane broadcast)
    f32x4 fk4[2];
#pragma unroll
    for (int nt = 0; nt < 2; nt++)
      fk4[nt] = *(const f32x4*)(fl + kbase + kh * 32 + nt * 16 + quad * 4);

#pragma unroll
    for (int g = 0; g < 2; g++) {
      float fqg = fq[g];
      // wrd = [A0, A1, B0, B1]: A_m from nt0 keys {4q+2m,+1}, B_m from nt1.
      unsigned int wrd[4];
#pragma unroll
      for (int nt = 0; nt < 2; nt++) {
        // S^T tile: D[row=key_loc=nt*16+quad*4+r][col=q=l15], log2 domain
        f32x4 s = zero4;
        s = __builtin_amdgcn_mfma_f32_16x16x32_bf16(kf0[nt], qf[g][0], s, 0, 0, 0);
        s = __builtin_amdgcn_mfma_f32_16x16x32_bf16(kf1[nt], qf[g][1], s, 0, 0, 0);
        float p[4];
#pragma unroll
        for (int r = 0; r < 4; r++) {
          float dd = fk4[nt][r] - fqg;
          p[r] = __builtin_amdgcn_exp2f(
              fmaf(c2, __builtin_fabsf(dd), fmaf(c1, dd, s[r])));
        }
        unsigned int w0, w1;
        asm("v_cvt_pk_bf16_f32 %0, %1, %2" : "=v"(w0) : "v"(p[0]), "v"(p[1]));
        asm("v_cvt_pk_bf16_f32 %0, %1, %2" : "=v"(w1) : "v"(p[2]), "v"(p[3]));
        wrd[nt * 2 + 0] = w0;
        wrd[nt * 2 + 1] = w1;
      }
      // In-register P transpose. permlane32_swap: X'={Xq0,Xq1,Yq0,Yq1},
      // Y'={Xq2,Xq3,Yq2,Yq3}. permlane16_swap: X''={X'r0,Y'r0,X'r2,Y'r2},
      // Y''={X'r1,Y'r1,X'r3,Y'r3}. (A0,B0)->(W0,W2); (A1,B1)->(W1,W3):
      // lane quad q ends with keys {8q..8q+7} = PV A-frag for m=l15.
      asm("v_permlane32_swap_b32 %0, %1" : "+v"(wrd[0]), "+v"(wrd[2]));
      asm("v_permlane16_swap_b32 %0, %1" : "+v"(wrd[0]), "+v"(wrd[2]));
      asm("v_permlane32_swap_b32 %0, %1" : "+v"(wrd[1]), "+v"(wrd[3]));
      asm("v_permlane16_swap_b32 %0, %1" : "+v"(wrd[1]), "+v"(wrd[3]));
      u32x4v pw_;
      pw_.x = wrd[0]; pw_.y = wrd[1]; pw_.z = wrd[2]; pw_.w = wrd[3];
      bf8v pf = __builtin_bit_cast(bf8v, pw_);
      // O_g += P_g @ V_half ; l_g += P_g @ ones.
      o_l[g] = __builtin_amdgcn_mfma_f32_16x16x32_bf16(pf, onesv, o_l[g], 0, 0, 0);
#pragma unroll
      for (int dt = 0; dt < 4; dt++)
        o[g][dt] = __builtin_amdgcn_mfma_f32_16x16x32_bf16(pf, vf[dt],
                                                           o[g][dt], 0, 0, 0);
    }
    __syncthreads(); // drains this iter's DMA (vmcnt) + frees cur buf
  }

  // ---- merge key halves. kh==1 waves publish (O,l); kh==0 combine+store.
  float* Of = (float*)smem;             // [128 q][66] f32 = 33792 B
  float* Lf = (float*)(smem + 16896);   // 128 f32
  if (kh == 1) {
#pragma unroll
    for (int g = 0; g < 2; g++)
#pragma unroll
      for (int r = 0; r < 4; r++) {
        int ql = qw * 32 + g * 16 + quad * 4 + r;
#pragma unroll
        for (int dt = 0; dt < 4; dt++)
          Of[ql * 66 + dt * 16 + l15] = o[g][dt][r];
        if (l15 == 0) Lf[ql] = o_l[g][r];
      }
  }
  __syncthreads();
  if (kh == 0) {
#pragma unroll
    for (int g = 0; g < 2; g++)
#pragma unroll
      for (int r = 0; r < 4; r++) {
        int ql = qw * 32 + g * 16 + quad * 4 + r;
        float linv = 1.0f / (o_l[g][r] + Lf[ql]);
        __bf16* orow =
            (__bf16*)(ctx + (size_t)(b * T_SEQ + q0 + ql) * D_MODEL + h * HDIM);
#pragma unroll
        for (int dt = 0; dt < 4; dt++)
          orow[dt * 16 + l15] =
              (__bf16)((o[g][dt][r] + Of[ql * 66 + dt * 16 + l15]) * linv);
      }
  }
}

// ---------------------------------------------------------------------------
extern "C" void kernel_launch(void* const* d_in, const int* in_sizes, int n_in,
                              void* d_out, int out_size, void* d_ws,
                              size_t ws_size, hipStream_t stream) {
  const float* q = (const float*)d_in[0];
  const float* k = (const float*)d_in[1];
  const float* v = (const float*)d_in[2];
  const float* frac = (const float*)d_in[3];
  const float* Wq = (const float*)d_in[4];
  const float* Wk = (const float*)d_in[5];
  const float* Wv = (const float*)d_in[6];
  const float* Wo = (const float*)d_in[7];
  const float* bq = (const float*)d_in[8];
  const float* bk = (const float*)d_in[9];
  const float* bv = (const float*)d_in[10];
  const float* bo = (const float*)d_in[11];
  const float* alpha_pos = (const float*)d_in[12];
  const float* alpha_neg = (const float*)d_in[13];

  char* ws = (char*)d_ws;
  u16* Xb = (u16*)(ws + 0);
  u16* Wt = (u16*)(ws + 25165824);
  u16* Qr = (u16*)(ws + 33554432);
  u16* Kr = (u16*)(ws + 41943040);
  u16* Vtmp = (u16*)(ws + 50331648); // holds ctx
  u16* Vb = (u16*)(ws + 58720256);
  float* ctab = (float*)(ws + 67108864);
  float* stab = (float*)(ws + 67371008);
  u16* ctx = Vtmp;
  u16* QKVout = Qr; // Qr,Kr contiguous; z==2 writes Vb directly

  k_prep<<<dim3(7424), 256, 0, stream>>>(q, k, v, Wq, Wk, Wv, Wo, Xb, Wt, ctab,
                                         stab);
  k_gemm_qkv<<<dim3(8, 32, 3), 256, 0, stream>>>(Xb, Wt, bq, bk, bv, ctab, stab,
                                                 QKVout, Vb);
  k_attn<<<dim3(16, 32), 512, 0, stream>>>(Qr, Kr, Vb, frac, alpha_pos,
                                           alpha_neg, ctx);
  k_gemm_out<<<dim3(16, 64), 256, 0, stream>>>(ctx, Wt + 3 * 1048576, bo,
                                               (float*)d_out);
}